// Round 4
// baseline (681.947 us; speedup 1.0000x reference)
//
#include <hip/hip_runtime.h>
#include <stdint.h>

#define D_IN  128
#define D_OUT 64
#define NEG_SLOPE 0.2f
#define SUB       8      // (fallback path) sub-bins per key
#define SUB_SHIFT 3
#define SCAN_CHUNK 4096
#define RPW       8      // rows per wave in msg_score8
#define RPB       32     // rows per block

// ---- R11 sort path ----
#define CHUNK   3072     // edges per kpart2 block (LDS sp = 48KB, proven size)
#define UPT     12       // CHUNK / 256 entries per thread
#define GS_R    5        // rows: group = r>>5  -> 625 groups of 32 keys
#define GS_C    7        // cols: group = c>>7  -> 782 groups of 128 keys
#define CAPB_R  3712     // LDS accum capacity per row-group (mean 3200, +9 sigma)
#define CAPB_C  3072     // LDS accum capacity per col-group (mean 2560, +10 sigma)

// ---------------------------------------------------------------------------
// Fused skinny GEMM + attention score, 8 rows per wave, x staged in LDS.
// NUMERICS ARE BITWISE-IDENTICAL to the R4/R6/R7 passing path (absmax=128).
// DO NOT reassociate (R5 failed at 768 from an algebraically-equal variant).
// ---------------------------------------------------------------------------
__global__ void msg_score8_kernel(const float* __restrict__ x,
                                  const float* __restrict__ w,
                                  const float* __restrict__ att, int att_off,
                                  float* __restrict__ msg,
                                  float* __restrict__ score,
                                  int n_rows) {
    __shared__ float wl[D_IN * D_OUT];           // 32 KB
    __shared__ float xs[RPB * D_IN];             // 16 KB
    const int tid = threadIdx.x;

    const float4* w4  = (const float4*)w;
    float4*       wl4 = (float4*)wl;
#pragma unroll
    for (int i = 0; i < 8; ++i) wl4[tid + i * 256] = w4[tid + i * 256];

    const int rb = blockIdx.x * RPB;
    float4* xs4 = (float4*)xs;
    const float4* x4 = (const float4*)x;
#pragma unroll
    for (int i = 0; i < 4; ++i) {
        const int f  = tid + i * 256;
        const int r  = f >> 5;
        const int k4 = f & 31;
        const int row = min(rb + r, n_rows - 1);
        xs4[f] = x4[(size_t)row * 32 + k4];
    }
    __syncthreads();

    const int wv = tid >> 6;
    const int j  = tid & 63;
    const int rl = wv * RPW;
    const float4* xw = (const float4*)(xs + rl * D_IN);

    float acc[RPW];
#pragma unroll
    for (int r = 0; r < RPW; ++r) acc[r] = 0.f;

#pragma unroll 2
    for (int k4 = 0; k4 < D_IN / 4; ++k4) {
        const float w0 = wl[(k4 * 4 + 0) * D_OUT + j];
        const float w1 = wl[(k4 * 4 + 1) * D_OUT + j];
        const float w2 = wl[(k4 * 4 + 2) * D_OUT + j];
        const float w3 = wl[(k4 * 4 + 3) * D_OUT + j];
#pragma unroll
        for (int r = 0; r < RPW; ++r) {
            const float4 xv = xw[r * 32 + k4];
            acc[r] += xv.x * w0;
            acc[r] += xv.y * w1;
            acc[r] += xv.z * w2;
            acc[r] += xv.w * w3;
        }
    }

    const float aj = att[att_off + j];
#pragma unroll
    for (int r = 0; r < RPW; ++r) {
        const int row = rb + rl + r;
        if (row < n_rows) msg[(size_t)row * D_OUT + j] = acc[r];
        float v = acc[r] * aj;
#pragma unroll
        for (int off = 32; off > 0; off >>= 1) v += __shfl_down(v, off, 64);
        if (j == 0 && row < n_rows) score[row] = v;
    }
}

// ---------------------------------------------------------------------------
// R11 stage 1: ONE fused partition kernel for BOTH directions.
// Loads indices/nbhd/scores once into registers, computes e once (bitwise-
// same expression as proven path: s_score[c]+t_score[r]), then runs the
// proven LDS counting-sort + SEQUENTIAL coalesced dump twice (row groups,
// then col groups). Index is written TRANSPOSED [chunk][group] so the write
// is coalesced and kaccum's (s,e2) pair lands in one cache line.
// ---------------------------------------------------------------------------
__global__ void __launch_bounds__(256)
kpart2_kernel(const int* __restrict__ row_idx,
              const int* __restrict__ col_idx,
              const float* __restrict__ nbhd,
              const float* __restrict__ s_score,
              const float* __restrict__ t_score,
              float4* __restrict__ pay_r, int* __restrict__ idx_r,
              float4* __restrict__ pay_c, int* __restrict__ idx_c,
              int nnz, int ngr, int ngc) {
    extern __shared__ char sm[];
    float4* sp  = (float4*)sm;                       // CHUNK entries (48KB)
    int*    cnt = (int*)(sm + (size_t)CHUNK * 16);   // max(ngr,ngc)+1
    int*    off = cnt + (ngc + 1);                   // ngc >= ngr

    const int tid  = threadIdx.x;
    const int base = blockIdx.x * CHUNK;
    const int lim  = min(CHUNK, nnz - base);

    int   rr[UPT], cc[UPT];
    float ee[UPT], bb[UPT];
#pragma unroll
    for (int u = 0; u < UPT; ++u) {
        const int k = tid + u * 256;
        rr[u] = 0; cc[u] = 0; ee[u] = 0.f; bb[u] = 0.f;
        if (k < lim) {
            const int r = row_idx[base + k];
            const int c = col_idx[base + k];
            rr[u] = r; cc[u] = c; bb[u] = nbhd[base + k];
            const float xv = s_score[c] + t_score[r];
            ee[u] = xv >= 0.f ? xv : NEG_SLOPE * xv;
        }
    }

#pragma unroll 1
    for (int d = 0; d < 2; ++d) {
        const int gs   = d ? GS_C : GS_R;
        const int ng   = d ? ngc : ngr;
        const int mask = (1 << gs) - 1;
        float4* pd = d ? pay_c : pay_r;
        int*    id = d ? idx_c : idx_r;

        for (int k = tid; k <= ng; k += 256) cnt[k] = 0;
        __syncthreads();

#pragma unroll
        for (int u = 0; u < UPT; ++u) {
            const int k = tid + u * 256;
            if (k < lim) atomicAdd(&cnt[(d ? cc[u] : rr[u]) >> gs], 1);
        }
        __syncthreads();

        if (tid == 0) {
            int a = 0;
            for (int k = 0; k < ng; ++k) { const int t = cnt[k]; off[k] = a; cnt[k] = a; a += t; }
            off[ng] = a;
        }
        __syncthreads();

#pragma unroll
        for (int u = 0; u < UPT; ++u) {
            const int k = tid + u * 256;
            if (k < lim) {
                const int key = d ? cc[u] : rr[u];
                const int oth = d ? rr[u] : cc[u];
                const int pos = atomicAdd(&cnt[key >> gs], 1);
                sp[pos] = make_float4(__int_as_float(oth | ((key & mask) << 20)),
                                      ee[u], bb[u], 0.f);
            }
        }
        __syncthreads();

        // sequential dump: fully coalesced full-line stores
        for (int k = tid; k < lim; k += 256) pd[(size_t)base + k] = sp[k];
        // transposed index: coalesced write, line-local read in kaccum
        for (int k = tid; k <= ng; k += 256)
            id[(size_t)blockIdx.x * (ng + 1) + k] = off[k];
        __syncthreads();
    }
}

// ---------------------------------------------------------------------------
// R11 stage 2: per-group accumulate, SINGLE payload pass.
// Quad-cooperative segment reads (4 lanes/chunk, consecutive entries ->
// ~1 line per quad-step instead of 1 line per entry). Entries land in LDS
// SoA in arrival order with on-the-fly histogram; a 16-bit permutation
// (not a physical re-sort) delivers sorted-by-key order to phase D.
// Phase D is the VERBATIM proven accum (f64 ers, same weight formula,
// 16-lane gather + butterfly) reading through perm[].
// ---------------------------------------------------------------------------
__global__ void __launch_bounds__(256)
kaccum_kernel(const float4* __restrict__ pay,
              const int* __restrict__ index, int ngp1,
              const float* __restrict__ other_msg,
              float* __restrict__ out,
              int NB, int kpg, int n_keys, int cap) {
    extern __shared__ char sm[];
    int*    PO   = (int*)sm;                                  // cap
    float*  E    = (float*)(sm + (size_t)cap * 4);            // cap
    float*  B    = (float*)(sm + (size_t)cap * 8);            // cap
    unsigned short* perm = (unsigned short*)(sm + (size_t)cap * 12); // cap
    int*    scnt = (int*)(sm + (size_t)cap * 14);             // kpg
    int*    soff = scnt + kpg;                                // kpg+1
    int*    scur = soff + kpg + 1;                            // kpg
    int*    tot  = scur + kpg;                                // 1

    const int g    = blockIdx.x;
    const int tid  = threadIdx.x;
    const int mask = kpg - 1;

    for (int k = tid; k < kpg; k += 256) scnt[k] = 0;
    if (tid == 0) tot[0] = 0;
    __syncthreads();

    // single payload pass: 4 lanes per chunk, bulk-reserved arrival slots
    for (int b0 = 0; b0 < NB; b0 += 64) {
        const int b = b0 + (tid >> 2);
        if (b < NB) {
            const int s   = index[(size_t)b * ngp1 + g];
            const int e2  = index[(size_t)b * ngp1 + g + 1];
            const int q   = tid & 3;
            const int rem = e2 - s - q;
            if (rem > 0) {
                const int n_my = (rem + 3) >> 2;
                int pos = atomicAdd(tot, n_my);
                int k = s + q;
                for (int u = 0; u < n_my; ++u, k += 4, ++pos) {
                    if (pos < cap) {
                        const float4 p = pay[(size_t)b * CHUNK + k];
                        const int pk = __float_as_int(p.x);
                        PO[pos] = pk; E[pos] = p.y; B[pos] = p.z;
                        atomicAdd(&scnt[(pk >> 20) & mask], 1);
                    }
                }
            }
        }
    }
    __syncthreads();

    if (tid == 0) {
        int a = 0;
        for (int k = 0; k < kpg; ++k) { const int t = scnt[k]; soff[k] = a; scur[k] = a; a += t; }
        soff[kpg] = a;
    }
    __syncthreads();

    // build 16-bit permutation: sorted position -> arrival index
    const int total = min(tot[0], cap);
    for (int k = tid; k < total; k += 256) {
        const int lr = (PO[k] >> 20) & mask;
        perm[atomicAdd(&scur[lr], 1)] = (unsigned short)k;
    }
    __syncthreads();

    // phase D: proven accum structure, wave per local key, perm indirection
    const int wv   = tid >> 6;
    const int lane = tid & 63;
    const int gg = lane >> 4;
    const int q  = lane & 15;
    const float4* msg4 = (const float4*)other_msg;

    for (int lr = wv; lr < kpg; lr += 4) {
        const int key = g * kpg + lr;
        if (key >= n_keys) continue;
        const int beg = soff[lr];
        const int end = soff[lr + 1];

        double psum = 0.0;
        for (int k = beg + lane; k < end; k += 64) psum += (double)E[perm[k]];
#pragma unroll
        for (int o = 32; o > 0; o >>= 1) psum += __shfl_down(psum, o, 64);
        double ers = __shfl(psum, 0, 64);
        if (ers == 0.0) ers = 1.0;
        const double inv = 1.0 / ers;

        float4 acc = make_float4(0.f, 0.f, 0.f, 0.f);
        for (int kb = beg; kb < end; kb += 64) {
            const int k = kb + lane;
            int o = 0; float wt = 0.f;
            if (k < end) {
                const int kk = perm[k];
                o  = PO[kk] & 0xFFFFF;
                wt = (float)((double)E[kk] * inv) * B[kk];
            }
            const int cnt2 = min(64, end - kb);
            for (int j = 0; j < cnt2; j += 4) {
                const int   jj = j + gg;
                const int   oj = __shfl(o,  jj, 64);
                const float wj = __shfl(wt, jj, 64);
                const float4 m = msg4[((size_t)oj << 4) + q];
                acc.x += wj * m.x;
                acc.y += wj * m.y;
                acc.z += wj * m.z;
                acc.w += wj * m.w;
            }
        }

#pragma unroll
        for (int d = 16; d < 64; d <<= 1) {
            acc.x += __shfl_xor(acc.x, d, 64);
            acc.y += __shfl_xor(acc.y, d, 64);
            acc.z += __shfl_xor(acc.z, d, 64);
            acc.w += __shfl_xor(acc.w, d, 64);
        }
        if (gg == 0)
            ((float4*)out)[((size_t)key << 4) + q] = acc;
    }
}

// ===========================================================================
// FALLBACK PATH (R7, proven): hist -> scan -> per-direction scatter -> accum.
// Used only if ws_size can't hold the sort-path payload (~100 MB).
// ===========================================================================
__global__ void hist_kernel(const int* __restrict__ row_idx,
                            const int* __restrict__ col_idx,
                            int* __restrict__ cnt, int col_base, int nnz) {
    const int i = blockIdx.x * blockDim.x + threadIdx.x;
    if (i >= nnz) return;
    const int s = i & (SUB - 1);
    atomicAdd(&cnt[(row_idx[i] << SUB_SHIFT) + s], 1);
    atomicAdd(&cnt[col_base + (col_idx[i] << SUB_SHIFT) + s], 1);
}

__global__ void scan_stage1(const int* __restrict__ cnt, int* __restrict__ bsum,
                            int n) {
    __shared__ int lds[256];
    const int t = threadIdx.x;
    const int base = blockIdx.x * SCAN_CHUNK;
    int s = 0;
    for (int k = t; k < SCAN_CHUNK; k += 256) {
        const int j = base + k;
        if (j < n) s += cnt[j];
    }
    lds[t] = s;
    __syncthreads();
    for (int d = 128; d > 0; d >>= 1) {
        if (t < d) lds[t] += lds[t + d];
        __syncthreads();
    }
    if (t == 0) bsum[blockIdx.x] = lds[0];
}

__global__ void scan_stage2(int* __restrict__ bsum, int nb) {
    __shared__ int lds[1024];
    const int t = threadIdx.x;
    const int v = (t < nb) ? bsum[t] : 0;
    lds[t] = v;
    __syncthreads();
    for (int d = 1; d < 1024; d <<= 1) {
        int u = (t >= d) ? lds[t - d] : 0;
        __syncthreads();
        lds[t] += u;
        __syncthreads();
    }
    if (t < nb) bsum[t] = lds[t] - v;
}

__global__ void scan_stage3(const int* __restrict__ cnt,
                            const int* __restrict__ bsum,
                            int* __restrict__ off, int* __restrict__ cur,
                            int n, int total) {
    __shared__ int lds[256];
    const int t = threadIdx.x;
    const int base = blockIdx.x * SCAN_CHUNK + t * 16;
    int c[16];
    int s = 0;
#pragma unroll
    for (int k = 0; k < 16; ++k) {
        const int j = base + k;
        c[k] = (j < n) ? cnt[j] : 0;
        s += c[k];
    }
    lds[t] = s;
    __syncthreads();
    for (int d = 1; d < 256; d <<= 1) {
        int u = (t >= d) ? lds[t - d] : 0;
        __syncthreads();
        lds[t] += u;
        __syncthreads();
    }
    int ex = bsum[blockIdx.x] + lds[t] - s;
#pragma unroll
    for (int k = 0; k < 16; ++k) {
        const int j = base + k;
        if (j < n) { off[j] = ex; cur[j] = ex; ex += c[k]; }
    }
    if (blockIdx.x == 0 && t == 0) off[n] = total;
}

__global__ void scatter_row_kernel(const int* __restrict__ row_idx,
                                   const int* __restrict__ col_idx,
                                   const float* __restrict__ nbhd,
                                   const float* __restrict__ s_score,
                                   const float* __restrict__ t_score,
                                   int* __restrict__ cur,
                                   float4* __restrict__ pay, int nnz) {
    const int i = blockIdx.x * blockDim.x + threadIdx.x;
    if (i >= nnz) return;
    const int r = row_idx[i];
    const int c = col_idx[i];
    const float xv = s_score[c] + t_score[r];
    const float e  = xv >= 0.f ? xv : NEG_SLOPE * xv;
    const int p = atomicAdd(&cur[(r << SUB_SHIFT) + (i & (SUB - 1))], 1);
    pay[p] = make_float4(__int_as_float(c), e, nbhd[i], 0.f);
}

__global__ void scatter_col_kernel(const int* __restrict__ row_idx,
                                   const int* __restrict__ col_idx,
                                   const float* __restrict__ nbhd,
                                   const float* __restrict__ s_score,
                                   const float* __restrict__ t_score,
                                   int* __restrict__ cur, int col_base,
                                   float4* __restrict__ pay, int nnz) {
    const int i = blockIdx.x * blockDim.x + threadIdx.x;
    if (i >= nnz) return;
    const int r = row_idx[i];
    const int c = col_idx[i];
    const float xv = s_score[c] + t_score[r];
    const float e  = xv >= 0.f ? xv : NEG_SLOPE * xv;
    const int p = atomicAdd(&cur[col_base + (c << SUB_SHIFT) + (i & (SUB - 1))], 1);
    pay[p] = make_float4(__int_as_float(r), e, nbhd[i], 0.f);
}

__global__ void accum_kernel(const int* __restrict__ off, int off_base,
                             const float4* __restrict__ pay,
                             const float* __restrict__ other_msg,
                             float* __restrict__ out, int n_mine) {
    const int wave = (int)((blockIdx.x * (size_t)blockDim.x + threadIdx.x) >> 6);
    const int lane = threadIdx.x & 63;
    if (wave >= n_mine) return;

    const int beg = off[off_base + (wave << SUB_SHIFT)];
    const int end = off[off_base + (wave << SUB_SHIFT) + SUB];

    double psum = 0.0;
    for (int k = beg + lane; k < end; k += 64) psum += (double)pay[k].y;
#pragma unroll
    for (int o = 32; o > 0; o >>= 1) psum += __shfl_down(psum, o, 64);
    double ers = __shfl(psum, 0, 64);
    if (ers == 0.0) ers = 1.0;
    const double inv = 1.0 / ers;

    const int g = lane >> 4;
    const int q = lane & 15;
    const float4* msg4 = (const float4*)other_msg;
    float4 acc = make_float4(0.f, 0.f, 0.f, 0.f);

    for (int kb = beg; kb < end; kb += 64) {
        const int k = kb + lane;
        int o = 0; float wt = 0.f;
        if (k < end) {
            float4 p = pay[k];
            o  = __float_as_int(p.x);
            wt = (float)((double)p.y * inv) * p.z;
        }
        const int cnt = min(64, end - kb);
        for (int j = 0; j < cnt; j += 4) {
            const int   jj = j + g;
            const int   oj = __shfl(o,  jj, 64);
            const float wj = __shfl(wt, jj, 64);
            float4 m = msg4[((size_t)oj << 4) + q];
            acc.x += wj * m.x;
            acc.y += wj * m.y;
            acc.z += wj * m.z;
            acc.w += wj * m.w;
        }
    }

#pragma unroll
    for (int d = 16; d < 64; d <<= 1) {
        acc.x += __shfl_xor(acc.x, d, 64);
        acc.y += __shfl_xor(acc.y, d, 64);
        acc.z += __shfl_xor(acc.z, d, 64);
        acc.w += __shfl_xor(acc.w, d, 64);
    }
    if (g == 0) ((float4*)out)[((size_t)wave << 4) + q] = acc;
}

// ---------------------------------------------------------------------------
extern "C" void kernel_launch(void* const* d_in, const int* in_sizes, int n_in,
                              void* d_out, int out_size, void* d_ws, size_t ws_size,
                              hipStream_t stream) {
    const float* x_source = (const float*)d_in[0];
    const float* x_target = (const float*)d_in[1];
    const float* nbhd     = (const float*)d_in[2];
    const float* w_s      = (const float*)d_in[3];
    const float* w_t      = (const float*)d_in[4];
    const float* att      = (const float*)d_in[5];
    const int*   row_idx  = (const int*)d_in[6];
    const int*   col_idx  = (const int*)d_in[7];

    const int n_s = in_sizes[0] / D_IN;   // 100000
    const int n_t = in_sizes[1] / D_IN;   // 20000
    const int nnz = in_sizes[2];          // 2000000

    float* out = (float*)d_out;
    float* mos = out;                          // (n_s, 64)
    float* mot = out + (size_t)n_s * D_OUT;    // (n_t, 64)

    // common workspace head
    char* ws = (char*)d_ws;
    float* s_msg   = (float*)ws;  ws += sizeof(float) * (size_t)n_s * D_OUT;
    float* t_msg   = (float*)ws;  ws += sizeof(float) * (size_t)n_t * D_OUT;
    float* s_score = (float*)ws;  ws += sizeof(float) * (size_t)n_s;
    float* t_score = (float*)ws;  ws += sizeof(float) * (size_t)n_t;

    // R11 sort-path tail
    const int NBCH = (nnz + CHUNK - 1) / CHUNK;          // 652
    const int NGR  = (n_t + (1 << GS_R) - 1) >> GS_R;    // 625
    const int NGC  = (n_s + (1 << GS_C) - 1) >> GS_C;    // 782
    char* wsb = ws;
    int* idx_r = (int*)wsb;  wsb += sizeof(int) * (size_t)NBCH * (NGR + 1);
    int* idx_c = (int*)wsb;  wsb += sizeof(int) * (size_t)NBCH * (NGC + 1);
    wsb = (char*)(((uintptr_t)wsb + 15) & ~(uintptr_t)15);
    float4* pay_r = (float4*)wsb;  wsb += sizeof(float4) * (size_t)NBCH * CHUNK;
    float4* pay_c = (float4*)wsb;  wsb += sizeof(float4) * (size_t)NBCH * CHUNK;
    const size_t need_sort = (size_t)(wsb - (char*)d_ws);

    // 1) messages + scores (bitwise-stable path)
    msg_score8_kernel<<<(n_s + RPB - 1) / RPB, 256, 0, stream>>>(
        x_source, w_s, att, 0, s_msg, s_score, n_s);
    msg_score8_kernel<<<(n_t + RPB - 1) / RPB, 256, 0, stream>>>(
        x_target, w_t, att, D_OUT, t_msg, t_score, n_t);

    if (ws_size >= need_sort) {
        // ---------------- R11 sort path ----------------
        const size_t smem_part = (size_t)CHUNK * 16 + 2 * (size_t)(NGC + 1) * 4;
        kpart2_kernel<<<NBCH, 256, smem_part, stream>>>(
            row_idx, col_idx, nbhd, s_score, t_score,
            pay_r, idx_r, pay_c, idx_c, nnz, NGR, NGC);

        const size_t smem_a_r = (size_t)CAPB_R * 14 + (size_t)(3 * (1 << GS_R) + 2) * 4;
        const size_t smem_a_c = (size_t)CAPB_C * 14 + (size_t)(3 * (1 << GS_C) + 2) * 4;
        kaccum_kernel<<<NGR, 256, smem_a_r, stream>>>(
            pay_r, idx_r, NGR + 1, s_msg, mot, NBCH, 1 << GS_R, n_t, CAPB_R);
        kaccum_kernel<<<NGC, 256, smem_a_c, stream>>>(
            pay_c, idx_c, NGC + 1, t_msg, mos, NBCH, 1 << GS_C, n_s, CAPB_C);
    } else {
        // ---------------- fallback: R7 hist+scan+sort path ----------------
        const int col_base = n_t * SUB;
        const int n_cnt    = (n_t + n_s) * SUB;
        const int total    = 2 * nnz;

        char* wsf = ws;
        int* cnt  = (int*)wsf;  wsf += sizeof(int) * (size_t)n_cnt;
        int* cur  = (int*)wsf;  wsf += sizeof(int) * (size_t)n_cnt;
        int* off  = (int*)wsf;  wsf += sizeof(int) * (size_t)(n_cnt + 1);
        int* bsum = (int*)wsf;  wsf += sizeof(int) * 1024;
        wsf = (char*)(((uintptr_t)wsf + 15) & ~(uintptr_t)15);
        float4* pay = (float4*)wsf;

        hipMemsetAsync(cnt, 0, sizeof(int) * (size_t)n_cnt, stream);

        hist_kernel<<<(nnz + 255) / 256, 256, 0, stream>>>(
            row_idx, col_idx, cnt, col_base, nnz);

        const int nb = (n_cnt + SCAN_CHUNK - 1) / SCAN_CHUNK;
        scan_stage1<<<nb, 256, 0, stream>>>(cnt, bsum, n_cnt);
        scan_stage2<<<1, 1024, 0, stream>>>(bsum, nb);
        scan_stage3<<<nb, 256, 0, stream>>>(cnt, bsum, off, cur, n_cnt, total);

        scatter_row_kernel<<<(nnz + 255) / 256, 256, 0, stream>>>(
            row_idx, col_idx, nbhd, s_score, t_score, cur, pay, nnz);
        scatter_col_kernel<<<(nnz + 255) / 256, 256, 0, stream>>>(
            row_idx, col_idx, nbhd, s_score, t_score, cur, col_base, pay, nnz);

        accum_kernel<<<(int)(((size_t)n_t * 64 + 255) / 256), 256, 0, stream>>>(
            off, 0, pay, s_msg, mot, n_t);
        accum_kernel<<<(int)(((size_t)n_s * 64 + 255) / 256), 256, 0, stream>>>(
            off, col_base, pay, t_msg, mos, n_s);
    }
}

// Round 5
// 634.987 us; speedup vs baseline: 1.0740x; 1.0740x over previous
//
#include <hip/hip_runtime.h>
#include <stdint.h>

#define D_IN  128
#define D_OUT 64
#define NEG_SLOPE 0.2f
#define SUB       8      // (fallback path) sub-bins per key
#define SUB_SHIFT 3
#define SCAN_CHUNK 4096
#define RPW       8      // rows per wave in msg_score8
#define RPB       32     // rows per block

// ---- R12 grouped-sort path ----
#define CHUNK   3072     // edges per chunk (LDS sp = 48KB, proven size)
#define UPT     12       // CHUNK / 256 entries per thread
#define GS_R    5        // rows: group = r>>5  -> 625 groups of 32 keys
#define GS_C    7        // cols: group = c>>7  -> 782 groups of 128 keys
#define CAPB_R  3712     // LDS accum capacity per row-group (mean 3200, +9 sigma)
#define CAPB_C  3072     // LDS accum capacity per col-group (mean 2560, +10 sigma)

// ---------------------------------------------------------------------------
// Fused skinny GEMM + attention score, 8 rows per wave, x staged in LDS.
// NUMERICS ARE BITWISE-IDENTICAL to the R4/R6/R7 passing path (absmax=128).
// DO NOT reassociate (R5 failed at 768 from an algebraically-equal variant).
// ---------------------------------------------------------------------------
__global__ void msg_score8_kernel(const float* __restrict__ x,
                                  const float* __restrict__ w,
                                  const float* __restrict__ att, int att_off,
                                  float* __restrict__ msg,
                                  float* __restrict__ score,
                                  int n_rows) {
    __shared__ float wl[D_IN * D_OUT];           // 32 KB
    __shared__ float xs[RPB * D_IN];             // 16 KB
    const int tid = threadIdx.x;

    const float4* w4  = (const float4*)w;
    float4*       wl4 = (float4*)wl;
#pragma unroll
    for (int i = 0; i < 8; ++i) wl4[tid + i * 256] = w4[tid + i * 256];

    const int rb = blockIdx.x * RPB;
    float4* xs4 = (float4*)xs;
    const float4* x4 = (const float4*)x;
#pragma unroll
    for (int i = 0; i < 4; ++i) {
        const int f  = tid + i * 256;
        const int r  = f >> 5;
        const int k4 = f & 31;
        const int row = min(rb + r, n_rows - 1);
        xs4[f] = x4[(size_t)row * 32 + k4];
    }
    __syncthreads();

    const int wv = tid >> 6;
    const int j  = tid & 63;
    const int rl = wv * RPW;
    const float4* xw = (const float4*)(xs + rl * D_IN);

    float acc[RPW];
#pragma unroll
    for (int r = 0; r < RPW; ++r) acc[r] = 0.f;

#pragma unroll 2
    for (int k4 = 0; k4 < D_IN / 4; ++k4) {
        const float w0 = wl[(k4 * 4 + 0) * D_OUT + j];
        const float w1 = wl[(k4 * 4 + 1) * D_OUT + j];
        const float w2 = wl[(k4 * 4 + 2) * D_OUT + j];
        const float w3 = wl[(k4 * 4 + 3) * D_OUT + j];
#pragma unroll
        for (int r = 0; r < RPW; ++r) {
            const float4 xv = xw[r * 32 + k4];
            acc[r] += xv.x * w0;
            acc[r] += xv.y * w1;
            acc[r] += xv.z * w2;
            acc[r] += xv.w * w3;
        }
    }

    const float aj = att[att_off + j];
#pragma unroll
    for (int r = 0; r < RPW; ++r) {
        const int row = rb + rl + r;
        if (row < n_rows) msg[(size_t)row * D_OUT + j] = acc[r];
        float v = acc[r] * aj;
#pragma unroll
        for (int off = 32; off > 0; off >>= 1) v += __shfl_down(v, off, 64);
        if (j == 0 && row < n_rows) score[row] = v;
    }
}

// ---------------------------------------------------------------------------
// R12 stage 1: per-chunk histograms for both directions in one pass.
// LDS hist -> coalesced row write of counts. No global atomics, no memset.
// ---------------------------------------------------------------------------
__global__ void __launch_bounds__(256)
khist2_kernel(const int* __restrict__ row_idx, const int* __restrict__ col_idx,
              int* __restrict__ cntR, int* __restrict__ cntC,
              int nnz, int ngr, int ngc) {
    extern __shared__ int hs[];
    int* hr = hs;
    int* hc = hs + ngr;
    const int tid  = threadIdx.x;
    const int base = blockIdx.x * CHUNK;
    const int lim  = min(CHUNK, nnz - base);

    for (int k = tid; k < ngr + ngc; k += 256) hs[k] = 0;
    __syncthreads();
    for (int k = tid; k < lim; k += 256) {
        atomicAdd(&hr[row_idx[base + k] >> GS_R], 1);
        atomicAdd(&hc[col_idx[base + k] >> GS_C], 1);
    }
    __syncthreads();
    for (int g = tid; g < ngr; g += 256) cntR[(size_t)blockIdx.x * ngr + g] = hr[g];
    for (int g = tid; g < ngc; g += 256) cntC[(size_t)blockIdx.x * ngc + g] = hc[g];
}

// ---------------------------------------------------------------------------
// R12 stage 2a: per-group totals (block per group, column sum over chunks).
// ---------------------------------------------------------------------------
__global__ void __launch_bounds__(256)
kgsum_kernel(const int* __restrict__ cnt, int* __restrict__ gtot,
             int NB, int ng) {
    __shared__ int lds[256];
    const int g = blockIdx.x;
    const int t = threadIdx.x;
    int s = 0;
    for (int b = t; b < NB; b += 256) s += cnt[(size_t)b * ng + g];
    lds[t] = s;
    __syncthreads();
    for (int d = 128; d > 0; d >>= 1) {
        if (t < d) lds[t] += lds[t + d];
        __syncthreads();
    }
    if (t == 0) gtot[g] = lds[0];
}

// ---------------------------------------------------------------------------
// R12 stage 2b: exclusive scan of group totals -> global group offsets.
// Grid = 2 blocks (block 0 = row dir, block 1 = col dir); n <= 1024.
// ---------------------------------------------------------------------------
__global__ void __launch_bounds__(1024)
kgscan2_kernel(const int* __restrict__ gtotR, int* __restrict__ goffR, int ngr,
               const int* __restrict__ gtotC, int* __restrict__ goffC, int ngc) {
    __shared__ int lds[1024];
    const int t = threadIdx.x;
    const int* gt = blockIdx.x ? gtotC : gtotR;
    int*       go = blockIdx.x ? goffC : goffR;
    const int  n  = blockIdx.x ? ngc : ngr;
    const int v = (t < n) ? gt[t] : 0;
    lds[t] = v;
    __syncthreads();
    for (int d = 1; d < 1024; d <<= 1) {
        int u = (t >= d) ? lds[t - d] : 0;
        __syncthreads();
        lds[t] += u;
        __syncthreads();
    }
    if (t < n) go[t] = lds[t] - v;
    if (t == n - 1) go[n] = lds[t];
}

// ---------------------------------------------------------------------------
// R12 stage 2c: per-(group,chunk) global positions.
// gpos layout [g][b] -> block g writes its row coalesced.
// ---------------------------------------------------------------------------
__global__ void __launch_bounds__(256)
kgpos_kernel(const int* __restrict__ cnt, const int* __restrict__ goff,
             int* __restrict__ gpos, int NB, int ng) {
    __shared__ int lds[256];
    const int g = blockIdx.x;
    const int t = threadIdx.x;
    int c[3];
    int s = 0;
#pragma unroll
    for (int u = 0; u < 3; ++u) {
        const int b = 3 * t + u;
        c[u] = (b < NB) ? cnt[(size_t)b * ng + g] : 0;
        s += c[u];
    }
    lds[t] = s;
    __syncthreads();
    for (int d = 1; d < 256; d <<= 1) {
        int u = (t >= d) ? lds[t - d] : 0;
        __syncthreads();
        lds[t] += u;
        __syncthreads();
    }
    int ex = goff[g] + lds[t] - s;
#pragma unroll
    for (int u = 0; u < 3; ++u) {
        const int b = 3 * t + u;
        if (b < NB) { gpos[(size_t)g * NB + b] = ex; ex += c[u]; }
    }
}

// ---------------------------------------------------------------------------
// R12 stage 3: chunk-local LDS counting sort (R11's proven machinery) +
// DIRECT grouped global write: each (group,chunk) segment goes to its exact
// global slot. Writes are piecewise-contiguous runs (~5 float4s), so the
// coalescer emits ~2 lines/segment instead of 1 line/entry, and abutting
// segments of concurrent neighbor chunks share boundary lines in L2.
// Entry: {oth | local<<20, e, nb, group}. e computed ONCE, bitwise-same
// expression as the proven path.
// ---------------------------------------------------------------------------
__global__ void __launch_bounds__(256)
kpart3_kernel(const int* __restrict__ row_idx,
              const int* __restrict__ col_idx,
              const float* __restrict__ nbhd,
              const float* __restrict__ s_score,
              const float* __restrict__ t_score,
              const int* __restrict__ gposR, const int* __restrict__ gposC,
              float4* __restrict__ pay_r, float4* __restrict__ pay_c,
              int nnz, int NB, int ngr, int ngc) {
    extern __shared__ char sm[];
    float4* sp   = (float4*)sm;                      // CHUNK entries (48KB)
    int*    cnt  = (int*)(sm + (size_t)CHUNK * 16);  // ngc+1
    int*    off  = cnt + (ngc + 1);                  // ngc+1
    int*    gofb = off + (ngc + 1);                  // ngc

    const int tid  = threadIdx.x;
    const int b    = blockIdx.x;
    const int base = b * CHUNK;
    const int lim  = min(CHUNK, nnz - base);

    int   rr[UPT], cc[UPT];
    float ee[UPT], bb[UPT];
#pragma unroll
    for (int u = 0; u < UPT; ++u) {
        const int k = tid + u * 256;
        rr[u] = 0; cc[u] = 0; ee[u] = 0.f; bb[u] = 0.f;
        if (k < lim) {
            const int r = row_idx[base + k];
            const int c = col_idx[base + k];
            rr[u] = r; cc[u] = c; bb[u] = nbhd[base + k];
            const float xv = s_score[c] + t_score[r];
            ee[u] = xv >= 0.f ? xv : NEG_SLOPE * xv;
        }
    }

#pragma unroll 1
    for (int d = 0; d < 2; ++d) {
        const int gs   = d ? GS_C : GS_R;
        const int ng   = d ? ngc : ngr;
        const int mask = (1 << gs) - 1;
        const int* gp  = d ? gposC : gposR;
        float4*    pd  = d ? pay_c : pay_r;

        for (int k = tid; k <= ng; k += 256) cnt[k] = 0;
        __syncthreads();

#pragma unroll
        for (int u = 0; u < UPT; ++u) {
            const int k = tid + u * 256;
            if (k < lim) atomicAdd(&cnt[(d ? cc[u] : rr[u]) >> gs], 1);
        }
        __syncthreads();

        if (tid == 0) {
            int a = 0;
            for (int k = 0; k < ng; ++k) { const int t = cnt[k]; off[k] = a; cnt[k] = a; a += t; }
            off[ng] = a;
        }
        __syncthreads();

        // prestage this chunk's global positions (strided read, L3-absorbed)
        for (int k = tid; k < ng; k += 256) gofb[k] = gp[(size_t)k * NB + b];

#pragma unroll
        for (int u = 0; u < UPT; ++u) {
            const int k = tid + u * 256;
            if (k < lim) {
                const int key = d ? cc[u] : rr[u];
                const int oth = d ? rr[u] : cc[u];
                const int grp = key >> gs;
                const int pos = atomicAdd(&cnt[grp], 1);
                sp[pos] = make_float4(__int_as_float(oth | ((key & mask) << 20)),
                                      ee[u], bb[u], __int_as_float(grp));
            }
        }
        __syncthreads();

        // grouped write: consecutive k within a segment -> consecutive dst
        for (int k = tid; k < lim; k += 256) {
            const float4 p = sp[k];
            const int grp = __float_as_int(p.w);
            pd[(size_t)gofb[grp] + (k - off[grp])] = p;
        }
        __syncthreads();
    }
}

// ---------------------------------------------------------------------------
// R12 stage 4: per-group accumulate over a DENSE contiguous payload range.
// One coalesced streaming load into LDS SoA (pos = k, no reservation atomic)
// with on-the-fly local-key histogram; 16-bit perm gives sorted order;
// phase D is the VERBATIM proven accum (f64 ers, same weight formula,
// 16-lane gather + butterfly).
// ---------------------------------------------------------------------------
__global__ void __launch_bounds__(256)
kaccum_kernel(const float4* __restrict__ pay,
              const int* __restrict__ goff,
              const float* __restrict__ other_msg,
              float* __restrict__ out,
              int kpg, int n_keys, int cap) {
    extern __shared__ char sm[];
    int*    PO   = (int*)sm;                                  // cap
    float*  E    = (float*)(sm + (size_t)cap * 4);            // cap
    float*  B    = (float*)(sm + (size_t)cap * 8);            // cap
    unsigned short* perm = (unsigned short*)(sm + (size_t)cap * 12); // cap
    int*    scnt = (int*)(sm + (size_t)cap * 14);             // kpg
    int*    soff = scnt + kpg;                                // kpg+1
    int*    scur = soff + kpg + 1;                            // kpg

    const int g    = blockIdx.x;
    const int tid  = threadIdx.x;
    const int mask = kpg - 1;

    const int beg = goff[g];
    const int n   = min(goff[g + 1] - beg, cap);

    for (int k = tid; k < kpg; k += 256) scnt[k] = 0;
    __syncthreads();

    // dense coalesced load + on-the-fly histogram
    for (int k = tid; k < n; k += 256) {
        const float4 p = pay[(size_t)beg + k];
        const int pk = __float_as_int(p.x);
        PO[k] = pk; E[k] = p.y; B[k] = p.z;
        atomicAdd(&scnt[(pk >> 20) & mask], 1);
    }
    __syncthreads();

    if (tid == 0) {
        int a = 0;
        for (int k = 0; k < kpg; ++k) { const int t = scnt[k]; soff[k] = a; scur[k] = a; a += t; }
        soff[kpg] = a;
    }
    __syncthreads();

    // build 16-bit permutation: sorted position -> arrival index
    for (int k = tid; k < n; k += 256) {
        const int lr = (PO[k] >> 20) & mask;
        perm[atomicAdd(&scur[lr], 1)] = (unsigned short)k;
    }
    __syncthreads();

    // phase D: proven accum structure, wave per local key, perm indirection
    const int wv   = tid >> 6;
    const int lane = tid & 63;
    const int gg = lane >> 4;
    const int q  = lane & 15;
    const float4* msg4 = (const float4*)other_msg;

    for (int lr = wv; lr < kpg; lr += 4) {
        const int key = g * kpg + lr;
        if (key >= n_keys) continue;
        const int b2  = soff[lr];
        const int end = soff[lr + 1];

        double psum = 0.0;
        for (int k = b2 + lane; k < end; k += 64) psum += (double)E[perm[k]];
#pragma unroll
        for (int o = 32; o > 0; o >>= 1) psum += __shfl_down(psum, o, 64);
        double ers = __shfl(psum, 0, 64);
        if (ers == 0.0) ers = 1.0;
        const double inv = 1.0 / ers;

        float4 acc = make_float4(0.f, 0.f, 0.f, 0.f);
        for (int kb = b2; kb < end; kb += 64) {
            const int k = kb + lane;
            int o = 0; float wt = 0.f;
            if (k < end) {
                const int kk = perm[k];
                o  = PO[kk] & 0xFFFFF;
                wt = (float)((double)E[kk] * inv) * B[kk];
            }
            const int cnt2 = min(64, end - kb);
            for (int j = 0; j < cnt2; j += 4) {
                const int   jj = j + gg;
                const int   oj = __shfl(o,  jj, 64);
                const float wj = __shfl(wt, jj, 64);
                const float4 m = msg4[((size_t)oj << 4) + q];
                acc.x += wj * m.x;
                acc.y += wj * m.y;
                acc.z += wj * m.z;
                acc.w += wj * m.w;
            }
        }

#pragma unroll
        for (int d = 16; d < 64; d <<= 1) {
            acc.x += __shfl_xor(acc.x, d, 64);
            acc.y += __shfl_xor(acc.y, d, 64);
            acc.z += __shfl_xor(acc.z, d, 64);
            acc.w += __shfl_xor(acc.w, d, 64);
        }
        if (gg == 0)
            ((float4*)out)[((size_t)key << 4) + q] = acc;
    }
}

// ===========================================================================
// FALLBACK PATH (R7, proven): hist -> scan -> per-direction scatter -> accum.
// Used only if ws_size can't hold the sort-path payload (~102 MB).
// ===========================================================================
__global__ void hist_kernel(const int* __restrict__ row_idx,
                            const int* __restrict__ col_idx,
                            int* __restrict__ cnt, int col_base, int nnz) {
    const int i = blockIdx.x * blockDim.x + threadIdx.x;
    if (i >= nnz) return;
    const int s = i & (SUB - 1);
    atomicAdd(&cnt[(row_idx[i] << SUB_SHIFT) + s], 1);
    atomicAdd(&cnt[col_base + (col_idx[i] << SUB_SHIFT) + s], 1);
}

__global__ void scan_stage1(const int* __restrict__ cnt, int* __restrict__ bsum,
                            int n) {
    __shared__ int lds[256];
    const int t = threadIdx.x;
    const int base = blockIdx.x * SCAN_CHUNK;
    int s = 0;
    for (int k = t; k < SCAN_CHUNK; k += 256) {
        const int j = base + k;
        if (j < n) s += cnt[j];
    }
    lds[t] = s;
    __syncthreads();
    for (int d = 128; d > 0; d >>= 1) {
        if (t < d) lds[t] += lds[t + d];
        __syncthreads();
    }
    if (t == 0) bsum[blockIdx.x] = lds[0];
}

__global__ void scan_stage2(int* __restrict__ bsum, int nb) {
    __shared__ int lds[1024];
    const int t = threadIdx.x;
    const int v = (t < nb) ? bsum[t] : 0;
    lds[t] = v;
    __syncthreads();
    for (int d = 1; d < 1024; d <<= 1) {
        int u = (t >= d) ? lds[t - d] : 0;
        __syncthreads();
        lds[t] += u;
        __syncthreads();
    }
    if (t < nb) bsum[t] = lds[t] - v;
}

__global__ void scan_stage3(const int* __restrict__ cnt,
                            const int* __restrict__ bsum,
                            int* __restrict__ off, int* __restrict__ cur,
                            int n, int total) {
    __shared__ int lds[256];
    const int t = threadIdx.x;
    const int base = blockIdx.x * SCAN_CHUNK + t * 16;
    int c[16];
    int s = 0;
#pragma unroll
    for (int k = 0; k < 16; ++k) {
        const int j = base + k;
        c[k] = (j < n) ? cnt[j] : 0;
        s += c[k];
    }
    lds[t] = s;
    __syncthreads();
    for (int d = 1; d < 256; d <<= 1) {
        int u = (t >= d) ? lds[t - d] : 0;
        __syncthreads();
        lds[t] += u;
        __syncthreads();
    }
    int ex = bsum[blockIdx.x] + lds[t] - s;
#pragma unroll
    for (int k = 0; k < 16; ++k) {
        const int j = base + k;
        if (j < n) { off[j] = ex; cur[j] = ex; ex += c[k]; }
    }
    if (blockIdx.x == 0 && t == 0) off[n] = total;
}

__global__ void scatter_row_kernel(const int* __restrict__ row_idx,
                                   const int* __restrict__ col_idx,
                                   const float* __restrict__ nbhd,
                                   const float* __restrict__ s_score,
                                   const float* __restrict__ t_score,
                                   int* __restrict__ cur,
                                   float4* __restrict__ pay, int nnz) {
    const int i = blockIdx.x * blockDim.x + threadIdx.x;
    if (i >= nnz) return;
    const int r = row_idx[i];
    const int c = col_idx[i];
    const float xv = s_score[c] + t_score[r];
    const float e  = xv >= 0.f ? xv : NEG_SLOPE * xv;
    const int p = atomicAdd(&cur[(r << SUB_SHIFT) + (i & (SUB - 1))], 1);
    pay[p] = make_float4(__int_as_float(c), e, nbhd[i], 0.f);
}

__global__ void scatter_col_kernel(const int* __restrict__ row_idx,
                                   const int* __restrict__ col_idx,
                                   const float* __restrict__ nbhd,
                                   const float* __restrict__ s_score,
                                   const float* __restrict__ t_score,
                                   int* __restrict__ cur, int col_base,
                                   float4* __restrict__ pay, int nnz) {
    const int i = blockIdx.x * blockDim.x + threadIdx.x;
    if (i >= nnz) return;
    const int r = row_idx[i];
    const int c = col_idx[i];
    const float xv = s_score[c] + t_score[r];
    const float e  = xv >= 0.f ? xv : NEG_SLOPE * xv;
    const int p = atomicAdd(&cur[col_base + (c << SUB_SHIFT) + (i & (SUB - 1))], 1);
    pay[p] = make_float4(__int_as_float(r), e, nbhd[i], 0.f);
}

__global__ void accum_kernel(const int* __restrict__ off, int off_base,
                             const float4* __restrict__ pay,
                             const float* __restrict__ other_msg,
                             float* __restrict__ out, int n_mine) {
    const int wave = (int)((blockIdx.x * (size_t)blockDim.x + threadIdx.x) >> 6);
    const int lane = threadIdx.x & 63;
    if (wave >= n_mine) return;

    const int beg = off[off_base + (wave << SUB_SHIFT)];
    const int end = off[off_base + (wave << SUB_SHIFT) + SUB];

    double psum = 0.0;
    for (int k = beg + lane; k < end; k += 64) psum += (double)pay[k].y;
#pragma unroll
    for (int o = 32; o > 0; o >>= 1) psum += __shfl_down(psum, o, 64);
    double ers = __shfl(psum, 0, 64);
    if (ers == 0.0) ers = 1.0;
    const double inv = 1.0 / ers;

    const int g = lane >> 4;
    const int q = lane & 15;
    const float4* msg4 = (const float4*)other_msg;
    float4 acc = make_float4(0.f, 0.f, 0.f, 0.f);

    for (int kb = beg; kb < end; kb += 64) {
        const int k = kb + lane;
        int o = 0; float wt = 0.f;
        if (k < end) {
            float4 p = pay[k];
            o  = __float_as_int(p.x);
            wt = (float)((double)p.y * inv) * p.z;
        }
        const int cnt = min(64, end - kb);
        for (int j = 0; j < cnt; j += 4) {
            const int   jj = j + g;
            const int   oj = __shfl(o,  jj, 64);
            const float wj = __shfl(wt, jj, 64);
            float4 m = msg4[((size_t)oj << 4) + q];
            acc.x += wj * m.x;
            acc.y += wj * m.y;
            acc.z += wj * m.z;
            acc.w += wj * m.w;
        }
    }

#pragma unroll
    for (int d = 16; d < 64; d <<= 1) {
        acc.x += __shfl_xor(acc.x, d, 64);
        acc.y += __shfl_xor(acc.y, d, 64);
        acc.z += __shfl_xor(acc.z, d, 64);
        acc.w += __shfl_xor(acc.w, d, 64);
    }
    if (g == 0) ((float4*)out)[((size_t)wave << 4) + q] = acc;
}

// ---------------------------------------------------------------------------
extern "C" void kernel_launch(void* const* d_in, const int* in_sizes, int n_in,
                              void* d_out, int out_size, void* d_ws, size_t ws_size,
                              hipStream_t stream) {
    const float* x_source = (const float*)d_in[0];
    const float* x_target = (const float*)d_in[1];
    const float* nbhd     = (const float*)d_in[2];
    const float* w_s      = (const float*)d_in[3];
    const float* w_t      = (const float*)d_in[4];
    const float* att      = (const float*)d_in[5];
    const int*   row_idx  = (const int*)d_in[6];
    const int*   col_idx  = (const int*)d_in[7];

    const int n_s = in_sizes[0] / D_IN;   // 100000
    const int n_t = in_sizes[1] / D_IN;   // 20000
    const int nnz = in_sizes[2];          // 2000000

    float* out = (float*)d_out;
    float* mos = out;                          // (n_s, 64)
    float* mot = out + (size_t)n_s * D_OUT;    // (n_t, 64)

    // common workspace head
    char* ws = (char*)d_ws;
    float* s_msg   = (float*)ws;  ws += sizeof(float) * (size_t)n_s * D_OUT;
    float* t_msg   = (float*)ws;  ws += sizeof(float) * (size_t)n_t * D_OUT;
    float* s_score = (float*)ws;  ws += sizeof(float) * (size_t)n_s;
    float* t_score = (float*)ws;  ws += sizeof(float) * (size_t)n_t;

    // R12 grouped-sort tail
    const int NBCH = (nnz + CHUNK - 1) / CHUNK;          // 652
    const int NGR  = (n_t + (1 << GS_R) - 1) >> GS_R;    // 625
    const int NGC  = (n_s + (1 << GS_C) - 1) >> GS_C;    // 782
    char* wsb = ws;
    int* cntR  = (int*)wsb;  wsb += sizeof(int) * (size_t)NBCH * NGR;
    int* cntC  = (int*)wsb;  wsb += sizeof(int) * (size_t)NBCH * NGC;
    int* gposR = (int*)wsb;  wsb += sizeof(int) * (size_t)NGR * NBCH;
    int* gposC = (int*)wsb;  wsb += sizeof(int) * (size_t)NGC * NBCH;
    int* gtotR = (int*)wsb;  wsb += sizeof(int) * (size_t)NGR;
    int* goffR = (int*)wsb;  wsb += sizeof(int) * (size_t)(NGR + 1);
    int* gtotC = (int*)wsb;  wsb += sizeof(int) * (size_t)NGC;
    int* goffC = (int*)wsb;  wsb += sizeof(int) * (size_t)(NGC + 1);
    wsb = (char*)(((uintptr_t)wsb + 15) & ~(uintptr_t)15);
    float4* pay_r = (float4*)wsb;  wsb += sizeof(float4) * (size_t)nnz;
    float4* pay_c = (float4*)wsb;  wsb += sizeof(float4) * (size_t)nnz;
    const size_t need_sort = (size_t)(wsb - (char*)d_ws);

    // 1) messages + scores (bitwise-stable path)
    msg_score8_kernel<<<(n_s + RPB - 1) / RPB, 256, 0, stream>>>(
        x_source, w_s, att, 0, s_msg, s_score, n_s);
    msg_score8_kernel<<<(n_t + RPB - 1) / RPB, 256, 0, stream>>>(
        x_target, w_t, att, D_OUT, t_msg, t_score, n_t);

    if (ws_size >= need_sort) {
        // ---------------- R12 grouped-sort path ----------------
        khist2_kernel<<<NBCH, 256, (size_t)(NGR + NGC) * 4, stream>>>(
            row_idx, col_idx, cntR, cntC, nnz, NGR, NGC);

        kgsum_kernel<<<NGR, 256, 0, stream>>>(cntR, gtotR, NBCH, NGR);
        kgsum_kernel<<<NGC, 256, 0, stream>>>(cntC, gtotC, NBCH, NGC);
        kgscan2_kernel<<<2, 1024, 0, stream>>>(gtotR, goffR, NGR, gtotC, goffC, NGC);
        kgpos_kernel<<<NGR, 256, 0, stream>>>(cntR, goffR, gposR, NBCH, NGR);
        kgpos_kernel<<<NGC, 256, 0, stream>>>(cntC, goffC, gposC, NBCH, NGC);

        const size_t smem_part = (size_t)CHUNK * 16 + (size_t)(3 * (NGC + 1)) * 4;
        kpart3_kernel<<<NBCH, 256, smem_part, stream>>>(
            row_idx, col_idx, nbhd, s_score, t_score,
            gposR, gposC, pay_r, pay_c, nnz, NBCH, NGR, NGC);

        const size_t smem_a_r = (size_t)CAPB_R * 14 + (size_t)(3 * (1 << GS_R) + 2) * 4;
        const size_t smem_a_c = (size_t)CAPB_C * 14 + (size_t)(3 * (1 << GS_C) + 2) * 4;
        kaccum_kernel<<<NGR, 256, smem_a_r, stream>>>(
            pay_r, goffR, s_msg, mot, 1 << GS_R, n_t, CAPB_R);
        kaccum_kernel<<<NGC, 256, smem_a_c, stream>>>(
            pay_c, goffC, t_msg, mos, 1 << GS_C, n_s, CAPB_C);
    } else {
        // ---------------- fallback: R7 hist+scan+sort path ----------------
        const int col_base = n_t * SUB;
        const int n_cnt    = (n_t + n_s) * SUB;
        const int total    = 2 * nnz;

        char* wsf = ws;
        int* cnt  = (int*)wsf;  wsf += sizeof(int) * (size_t)n_cnt;
        int* cur  = (int*)wsf;  wsf += sizeof(int) * (size_t)n_cnt;
        int* off  = (int*)wsf;  wsf += sizeof(int) * (size_t)(n_cnt + 1);
        int* bsum = (int*)wsf;  wsf += sizeof(int) * 1024;
        wsf = (char*)(((uintptr_t)wsf + 15) & ~(uintptr_t)15);
        float4* pay = (float4*)wsf;

        hipMemsetAsync(cnt, 0, sizeof(int) * (size_t)n_cnt, stream);

        hist_kernel<<<(nnz + 255) / 256, 256, 0, stream>>>(
            row_idx, col_idx, cnt, col_base, nnz);

        const int nb = (n_cnt + SCAN_CHUNK - 1) / SCAN_CHUNK;
        scan_stage1<<<nb, 256, 0, stream>>>(cnt, bsum, n_cnt);
        scan_stage2<<<1, 1024, 0, stream>>>(bsum, nb);
        scan_stage3<<<nb, 256, 0, stream>>>(cnt, bsum, off, cur, n_cnt, total);

        scatter_row_kernel<<<(nnz + 255) / 256, 256, 0, stream>>>(
            row_idx, col_idx, nbhd, s_score, t_score, cur, pay, nnz);
        scatter_col_kernel<<<(nnz + 255) / 256, 256, 0, stream>>>(
            row_idx, col_idx, nbhd, s_score, t_score, cur, col_base, pay, nnz);

        accum_kernel<<<(int)(((size_t)n_t * 64 + 255) / 256), 256, 0, stream>>>(
            off, 0, pay, s_msg, mot, n_t);
        accum_kernel<<<(int)(((size_t)n_s * 64 + 255) / 256), 256, 0, stream>>>(
            off, col_base, pay, t_msg, mos, n_s);
    }
}

// Round 7
// 529.335 us; speedup vs baseline: 1.2883x; 1.1996x over previous
//
#include <hip/hip_runtime.h>
#include <stdint.h>

#define D_IN  128
#define D_OUT 64
#define NEG_SLOPE 0.2f
#define SUB       8      // (fallback path) sub-bins per key
#define SUB_SHIFT 3
#define SCAN_CHUNK 4096
#define RPW       8      // rows per wave in msg_score8
#define RPB       32     // rows per block

// ---- R13 grouped-sort path ----
#define CHUNK   3072     // edges per chunk (LDS sp = 48KB, proven size)
#define UPT     12       // CHUNK / 256 entries per thread
#define GS_R    5        // rows: group = r>>5  -> 625 groups of 32 keys
#define GS_C    7        // cols: group = c>>7  -> 782 groups of 128 keys
#define CAPB_R  3712     // per row-group capacity (mean 3200, +9 sigma)
#define CAPB_C  3072     // per col-group capacity (mean 2560, +10 sigma)

// ---------------------------------------------------------------------------
// Fused skinny GEMM + attention score, 8 rows per wave, x staged in LDS.
// NUMERICS ARE BITWISE-IDENTICAL to the R4/R6/R7 passing path (absmax=128).
// DO NOT reassociate (R5 failed at 768 from an algebraically-equal variant).
// ---------------------------------------------------------------------------
__global__ void msg_score8_kernel(const float* __restrict__ x,
                                  const float* __restrict__ w,
                                  const float* __restrict__ att, int att_off,
                                  float* __restrict__ msg,
                                  float* __restrict__ score,
                                  int n_rows) {
    __shared__ float wl[D_IN * D_OUT];           // 32 KB
    __shared__ float xs[RPB * D_IN];             // 16 KB
    const int tid = threadIdx.x;

    const float4* w4  = (const float4*)w;
    float4*       wl4 = (float4*)wl;
#pragma unroll
    for (int i = 0; i < 8; ++i) wl4[tid + i * 256] = w4[tid + i * 256];

    const int rb = blockIdx.x * RPB;
    float4* xs4 = (float4*)xs;
    const float4* x4 = (const float4*)x;
#pragma unroll
    for (int i = 0; i < 4; ++i) {
        const int f  = tid + i * 256;
        const int r  = f >> 5;
        const int k4 = f & 31;
        const int row = min(rb + r, n_rows - 1);
        xs4[f] = x4[(size_t)row * 32 + k4];
    }
    __syncthreads();

    const int wv = tid >> 6;
    const int j  = tid & 63;
    const int rl = wv * RPW;
    const float4* xw = (const float4*)(xs + rl * D_IN);

    float acc[RPW];
#pragma unroll
    for (int r = 0; r < RPW; ++r) acc[r] = 0.f;

#pragma unroll 2
    for (int k4 = 0; k4 < D_IN / 4; ++k4) {
        const float w0 = wl[(k4 * 4 + 0) * D_OUT + j];
        const float w1 = wl[(k4 * 4 + 1) * D_OUT + j];
        const float w2 = wl[(k4 * 4 + 2) * D_OUT + j];
        const float w3 = wl[(k4 * 4 + 3) * D_OUT + j];
#pragma unroll
        for (int r = 0; r < RPW; ++r) {
            const float4 xv = xw[r * 32 + k4];
            acc[r] += xv.x * w0;
            acc[r] += xv.y * w1;
            acc[r] += xv.z * w2;
            acc[r] += xv.w * w3;
        }
    }

    const float aj = att[att_off + j];
#pragma unroll
    for (int r = 0; r < RPW; ++r) {
        const int row = rb + rl + r;
        if (row < n_rows) msg[(size_t)row * D_OUT + j] = acc[r];
        float v = acc[r] * aj;
#pragma unroll
        for (int off = 32; off > 0; off >>= 1) v += __shfl_down(v, off, 64);
        if (j == 0 && row < n_rows) score[row] = v;
    }
}

// ---------------------------------------------------------------------------
// R12 stage 1 (kept): per-chunk histograms for both directions in one pass.
// ---------------------------------------------------------------------------
__global__ void __launch_bounds__(256)
khist2_kernel(const int* __restrict__ row_idx, const int* __restrict__ col_idx,
              int* __restrict__ cntR, int* __restrict__ cntC,
              int nnz, int ngr, int ngc) {
    extern __shared__ int hs[];
    int* hr = hs;
    int* hc = hs + ngr;
    const int tid  = threadIdx.x;
    const int base = blockIdx.x * CHUNK;
    const int lim  = min(CHUNK, nnz - base);

    for (int k = tid; k < ngr + ngc; k += 256) hs[k] = 0;
    __syncthreads();
    for (int k = tid; k < lim; k += 256) {
        atomicAdd(&hr[row_idx[base + k] >> GS_R], 1);
        atomicAdd(&hc[col_idx[base + k] >> GS_C], 1);
    }
    __syncthreads();
    for (int g = tid; g < ngr; g += 256) cntR[(size_t)blockIdx.x * ngr + g] = hr[g];
    for (int g = tid; g < ngc; g += 256) cntC[(size_t)blockIdx.x * ngc + g] = hc[g];
}

__global__ void __launch_bounds__(256)
kgsum_kernel(const int* __restrict__ cnt, int* __restrict__ gtot,
             int NB, int ng) {
    __shared__ int lds[256];
    const int g = blockIdx.x;
    const int t = threadIdx.x;
    int s = 0;
    for (int b = t; b < NB; b += 256) s += cnt[(size_t)b * ng + g];
    lds[t] = s;
    __syncthreads();
    for (int d = 128; d > 0; d >>= 1) {
        if (t < d) lds[t] += lds[t + d];
        __syncthreads();
    }
    if (t == 0) gtot[g] = lds[0];
}

__global__ void __launch_bounds__(1024)
kgscan2_kernel(const int* __restrict__ gtotR, int* __restrict__ goffR, int ngr,
               const int* __restrict__ gtotC, int* __restrict__ goffC, int ngc) {
    __shared__ int lds[1024];
    const int t = threadIdx.x;
    const int* gt = blockIdx.x ? gtotC : gtotR;
    int*       go = blockIdx.x ? goffC : goffR;
    const int  n  = blockIdx.x ? ngc : ngr;
    const int v = (t < n) ? gt[t] : 0;
    lds[t] = v;
    __syncthreads();
    for (int d = 1; d < 1024; d <<= 1) {
        int u = (t >= d) ? lds[t - d] : 0;
        __syncthreads();
        lds[t] += u;
        __syncthreads();
    }
    if (t < n) go[t] = lds[t] - v;
    if (t == n - 1) go[n] = lds[t];
}

__global__ void __launch_bounds__(256)
kgpos_kernel(const int* __restrict__ cnt, const int* __restrict__ goff,
             int* __restrict__ gpos, int NB, int ng) {
    __shared__ int lds[256];
    const int g = blockIdx.x;
    const int t = threadIdx.x;
    int c[3];
    int s = 0;
#pragma unroll
    for (int u = 0; u < 3; ++u) {
        const int b = 3 * t + u;
        c[u] = (b < NB) ? cnt[(size_t)b * ng + g] : 0;
        s += c[u];
    }
    lds[t] = s;
    __syncthreads();
    for (int d = 1; d < 256; d <<= 1) {
        int u = (t >= d) ? lds[t - d] : 0;
        __syncthreads();
        lds[t] += u;
        __syncthreads();
    }
    int ex = goff[g] + lds[t] - s;
#pragma unroll
    for (int u = 0; u < 3; ++u) {
        const int b = 3 * t + u;
        if (b < NB) { gpos[(size_t)g * NB + b] = ex; ex += c[u]; }
    }
}

// ---------------------------------------------------------------------------
// R12 stage 3 (kept): chunk-local LDS counting sort + grouped global write.
// Entry: {oth | local<<20, e, nb, group}. e computed ONCE, bitwise-same
// expression as the proven path.
// ---------------------------------------------------------------------------
__global__ void __launch_bounds__(256)
kpart3_kernel(const int* __restrict__ row_idx,
              const int* __restrict__ col_idx,
              const float* __restrict__ nbhd,
              const float* __restrict__ s_score,
              const float* __restrict__ t_score,
              const int* __restrict__ gposR, const int* __restrict__ gposC,
              float4* __restrict__ pay_r, float4* __restrict__ pay_c,
              int nnz, int NB, int ngr, int ngc) {
    extern __shared__ char sm[];
    float4* sp   = (float4*)sm;                      // CHUNK entries (48KB)
    int*    cnt  = (int*)(sm + (size_t)CHUNK * 16);  // ngc+1
    int*    off  = cnt + (ngc + 1);                  // ngc+1
    int*    gofb = off + (ngc + 1);                  // ngc

    const int tid  = threadIdx.x;
    const int b    = blockIdx.x;
    const int base = b * CHUNK;
    const int lim  = min(CHUNK, nnz - base);

    int   rr[UPT], cc[UPT];
    float ee[UPT], bb[UPT];
#pragma unroll
    for (int u = 0; u < UPT; ++u) {
        const int k = tid + u * 256;
        rr[u] = 0; cc[u] = 0; ee[u] = 0.f; bb[u] = 0.f;
        if (k < lim) {
            const int r = row_idx[base + k];
            const int c = col_idx[base + k];
            rr[u] = r; cc[u] = c; bb[u] = nbhd[base + k];
            const float xv = s_score[c] + t_score[r];
            ee[u] = xv >= 0.f ? xv : NEG_SLOPE * xv;
        }
    }

#pragma unroll 1
    for (int d = 0; d < 2; ++d) {
        const int gs   = d ? GS_C : GS_R;
        const int ng   = d ? ngc : ngr;
        const int mask = (1 << gs) - 1;
        const int* gp  = d ? gposC : gposR;
        float4*    pd  = d ? pay_c : pay_r;

        for (int k = tid; k <= ng; k += 256) cnt[k] = 0;
        __syncthreads();

#pragma unroll
        for (int u = 0; u < UPT; ++u) {
            const int k = tid + u * 256;
            if (k < lim) atomicAdd(&cnt[(d ? cc[u] : rr[u]) >> gs], 1);
        }
        __syncthreads();

        if (tid == 0) {
            int a = 0;
            for (int k = 0; k < ng; ++k) { const int t = cnt[k]; off[k] = a; cnt[k] = a; a += t; }
            off[ng] = a;
        }
        __syncthreads();

        // prestage this chunk's global positions (strided read, L3-absorbed)
        for (int k = tid; k < ng; k += 256) gofb[k] = gp[(size_t)k * NB + b];

#pragma unroll
        for (int u = 0; u < UPT; ++u) {
            const int k = tid + u * 256;
            if (k < lim) {
                const int key = d ? cc[u] : rr[u];
                const int oth = d ? rr[u] : cc[u];
                const int grp = key >> gs;
                const int pos = atomicAdd(&cnt[grp], 1);
                sp[pos] = make_float4(__int_as_float(oth | ((key & mask) << 20)),
                                      ee[u], bb[u], __int_as_float(grp));
            }
        }
        __syncthreads();

        // grouped write: consecutive k within a segment -> consecutive dst
        for (int k = tid; k < lim; k += 256) {
            const float4 p = sp[k];
            const int grp = __float_as_int(p.w);
            pd[(size_t)gofb[grp] + (k - off[grp])] = p;
        }
        __syncthreads();
    }
}

// ---------------------------------------------------------------------------
// R13 stage 4: IN-PLACE per-group key sort. Dense read -> LDS SoA + on-the-
// fly histogram -> 16-bit perm -> dense sorted writeback (coalesced full
// lines) + exact per-key offsets koff[g*(kpg+1)+j]. No phase D here: this
// kernel exists so the accumulator can run LDS-free at full occupancy.
// ---------------------------------------------------------------------------
__global__ void __launch_bounds__(512)
ksort_kernel(float4* __restrict__ pay,
             const int* __restrict__ goff,
             int* __restrict__ koff,
             int kpg, int cap) {
    extern __shared__ char sm[];
    int*    PO   = (int*)sm;                                  // cap
    float*  E    = (float*)(sm + (size_t)cap * 4);            // cap
    float*  B    = (float*)(sm + (size_t)cap * 8);            // cap
    unsigned short* perm = (unsigned short*)(sm + (size_t)cap * 12); // cap
    int*    scnt = (int*)(sm + (size_t)cap * 14);             // kpg
    int*    soff = scnt + kpg;                                // kpg+1
    int*    scur = soff + kpg + 1;                            // kpg

    const int g    = blockIdx.x;
    const int tid  = threadIdx.x;
    const int mask = kpg - 1;

    const int beg = goff[g];
    const int n   = min(goff[g + 1] - beg, cap);

    for (int k = tid; k < kpg; k += 512) scnt[k] = 0;
    __syncthreads();

    for (int k = tid; k < n; k += 512) {
        const float4 p = pay[(size_t)beg + k];
        const int pk = __float_as_int(p.x);
        PO[k] = pk; E[k] = p.y; B[k] = p.z;
        atomicAdd(&scnt[(pk >> 20) & mask], 1);
    }
    __syncthreads();

    if (tid == 0) {
        int a = 0;
        for (int k = 0; k < kpg; ++k) { const int t = scnt[k]; soff[k] = a; scur[k] = a; a += t; }
        soff[kpg] = a;
    }
    __syncthreads();

    for (int k = tid; k < n; k += 512)
        perm[atomicAdd(&scur[(PO[k] >> 20) & mask], 1)] = (unsigned short)k;
    __syncthreads();

    // sorted dense writeback (all reads done before this point -> in-place ok)
    for (int k = tid; k < n; k += 512) {
        const int kk = perm[k];
        pay[(size_t)beg + k] = make_float4(__int_as_float(PO[kk]), E[kk], B[kk], 0.f);
    }
    for (int k = tid; k <= kpg; k += 512)
        koff[(size_t)g * (kpg + 1) + k] = beg + soff[k];
}

// ---------------------------------------------------------------------------
// R13 stage 5: accumulate — VERBATIM R7/R0 wave-per-key accum (f64 ers, same
// weight formula, 16-lane gather + butterfly), LDS-free, one wave per key,
// per-key payload now a dense contiguous global segment via koff.
// Only deltas from the proven kernel: segment bounds from koff, and the
// payload's .x carries local key in bits >=20, so o is masked to 20 bits.
// ---------------------------------------------------------------------------
__global__ void kaccum2_kernel(const int* __restrict__ koff, int kshift,
                               const float4* __restrict__ pay,
                               const float* __restrict__ other_msg,
                               float* __restrict__ out, int n_mine) {
    const int wave = (int)((blockIdx.x * (size_t)blockDim.x + threadIdx.x) >> 6);
    const int lane = threadIdx.x & 63;
    if (wave >= n_mine) return;

    const int kpg = 1 << kshift;
    const int grp = wave >> kshift;
    const int jk  = wave & (kpg - 1);
    const int beg = koff[(size_t)grp * (kpg + 1) + jk];
    const int end = koff[(size_t)grp * (kpg + 1) + jk + 1];

    double psum = 0.0;
    for (int k = beg + lane; k < end; k += 64) psum += (double)pay[k].y;
#pragma unroll
    for (int o = 32; o > 0; o >>= 1) psum += __shfl_down(psum, o, 64);
    double ers = __shfl(psum, 0, 64);
    if (ers == 0.0) ers = 1.0;
    const double inv = 1.0 / ers;

    const int g = lane >> 4;
    const int q = lane & 15;
    const float4* msg4 = (const float4*)other_msg;
    float4 acc = make_float4(0.f, 0.f, 0.f, 0.f);

    for (int kb = beg; kb < end; kb += 64) {
        const int k = kb + lane;
        int o = 0; float wt = 0.f;
        if (k < end) {
            float4 p = pay[k];
            o  = __float_as_int(p.x) & 0xFFFFF;
            wt = (float)((double)p.y * inv) * p.z;
        }
        const int cnt = min(64, end - kb);
        for (int j = 0; j < cnt; j += 4) {
            const int   jj = j + g;
            const int   oj = __shfl(o,  jj, 64);
            const float wj = __shfl(wt, jj, 64);
            float4 m = msg4[((size_t)oj << 4) + q];
            acc.x += wj * m.x;
            acc.y += wj * m.y;
            acc.z += wj * m.z;
            acc.w += wj * m.w;
        }
    }

#pragma unroll
    for (int d = 16; d < 64; d <<= 1) {
        acc.x += __shfl_xor(acc.x, d, 64);
        acc.y += __shfl_xor(acc.y, d, 64);
        acc.z += __shfl_xor(acc.z, d, 64);
        acc.w += __shfl_xor(acc.w, d, 64);
    }
    if (g == 0) ((float4*)out)[((size_t)wave << 4) + q] = acc;
}

// ===========================================================================
// FALLBACK PATH (R7, proven): hist -> scan -> per-direction scatter -> accum.
// Used only if ws_size can't hold the sort-path payload (~102 MB).
// ===========================================================================
__global__ void hist_kernel(const int* __restrict__ row_idx,
                            const int* __restrict__ col_idx,
                            int* __restrict__ cnt, int col_base, int nnz) {
    const int i = blockIdx.x * blockDim.x + threadIdx.x;
    if (i >= nnz) return;
    const int s = i & (SUB - 1);
    atomicAdd(&cnt[(row_idx[i] << SUB_SHIFT) + s], 1);
    atomicAdd(&cnt[col_base + (col_idx[i] << SUB_SHIFT) + s], 1);
}

__global__ void scan_stage1(const int* __restrict__ cnt, int* __restrict__ bsum,
                            int n) {
    __shared__ int lds[256];
    const int t = threadIdx.x;
    const int base = blockIdx.x * SCAN_CHUNK;
    int s = 0;
    for (int k = t; k < SCAN_CHUNK; k += 256) {
        const int j = base + k;
        if (j < n) s += cnt[j];
    }
    lds[t] = s;
    __syncthreads();
    for (int d = 128; d > 0; d >>= 1) {
        if (t < d) lds[t] += lds[t + d];
        __syncthreads();
    }
    if (t == 0) bsum[blockIdx.x] = lds[0];
}

__global__ void scan_stage2(int* __restrict__ bsum, int nb) {
    __shared__ int lds[1024];
    const int t = threadIdx.x;
    const int v = (t < nb) ? bsum[t] : 0;
    lds[t] = v;
    __syncthreads();
    for (int d = 1; d < 1024; d <<= 1) {
        int u = (t >= d) ? lds[t - d] : 0;
        __syncthreads();
        lds[t] += u;
        __syncthreads();
    }
    if (t < nb) bsum[t] = lds[t] - v;
}

__global__ void scan_stage3(const int* __restrict__ cnt,
                            const int* __restrict__ bsum,
                            int* __restrict__ off, int* __restrict__ cur,
                            int n, int total) {
    __shared__ int lds[256];
    const int t = threadIdx.x;
    const int base = blockIdx.x * SCAN_CHUNK + t * 16;
    int c[16];
    int s = 0;
#pragma unroll
    for (int k = 0; k < 16; ++k) {
        const int j = base + k;
        c[k] = (j < n) ? cnt[j] : 0;
        s += c[k];
    }
    lds[t] = s;
    __syncthreads();
    for (int d = 1; d < 256; d <<= 1) {
        int u = (t >= d) ? lds[t - d] : 0;
        __syncthreads();
        lds[t] += u;
        __syncthreads();
    }
    int ex = bsum[blockIdx.x] + lds[t] - s;
#pragma unroll
    for (int k = 0; k < 16; ++k) {
        const int j = base + k;
        if (j < n) { off[j] = ex; cur[j] = ex; ex += c[k]; }
    }
    if (blockIdx.x == 0 && t == 0) off[n] = total;
}

__global__ void scatter_row_kernel(const int* __restrict__ row_idx,
                                   const int* __restrict__ col_idx,
                                   const float* __restrict__ nbhd,
                                   const float* __restrict__ s_score,
                                   const float* __restrict__ t_score,
                                   int* __restrict__ cur,
                                   float4* __restrict__ pay, int nnz) {
    const int i = blockIdx.x * blockDim.x + threadIdx.x;
    if (i >= nnz) return;
    const int r = row_idx[i];
    const int c = col_idx[i];
    const float xv = s_score[c] + t_score[r];
    const float e  = xv >= 0.f ? xv : NEG_SLOPE * xv;
    const int p = atomicAdd(&cur[(r << SUB_SHIFT) + (i & (SUB - 1))], 1);
    pay[p] = make_float4(__int_as_float(c), e, nbhd[i], 0.f);
}

__global__ void scatter_col_kernel(const int* __restrict__ row_idx,
                                   const int* __restrict__ col_idx,
                                   const float* __restrict__ nbhd,
                                   const float* __restrict__ s_score,
                                   const float* __restrict__ t_score,
                                   int* __restrict__ cur, int col_base,
                                   float4* __restrict__ pay, int nnz) {
    const int i = blockIdx.x * blockDim.x + threadIdx.x;
    if (i >= nnz) return;
    const int r = row_idx[i];
    const int c = col_idx[i];
    const float xv = s_score[c] + t_score[r];
    const float e  = xv >= 0.f ? xv : NEG_SLOPE * xv;
    const int p = atomicAdd(&cur[col_base + (c << SUB_SHIFT) + (i & (SUB - 1))], 1);
    pay[p] = make_float4(__int_as_float(r), e, nbhd[i], 0.f);
}

__global__ void accum_kernel(const int* __restrict__ off, int off_base,
                             const float4* __restrict__ pay,
                             const float* __restrict__ other_msg,
                             float* __restrict__ out, int n_mine) {
    const int wave = (int)((blockIdx.x * (size_t)blockDim.x + threadIdx.x) >> 6);
    const int lane = threadIdx.x & 63;
    if (wave >= n_mine) return;

    const int beg = off[off_base + (wave << SUB_SHIFT)];
    const int end = off[off_base + (wave << SUB_SHIFT) + SUB];

    double psum = 0.0;
    for (int k = beg + lane; k < end; k += 64) psum += (double)pay[k].y;
#pragma unroll
    for (int o = 32; o > 0; o >>= 1) psum += __shfl_down(psum, o, 64);
    double ers = __shfl(psum, 0, 64);
    if (ers == 0.0) ers = 1.0;
    const double inv = 1.0 / ers;

    const int g = lane >> 4;
    const int q = lane & 15;
    const float4* msg4 = (const float4*)other_msg;
    float4 acc = make_float4(0.f, 0.f, 0.f, 0.f);

    for (int kb = beg; kb < end; kb += 64) {
        const int k = kb + lane;
        int o = 0; float wt = 0.f;
        if (k < end) {
            float4 p = pay[k];
            o  = __float_as_int(p.x);
            wt = (float)((double)p.y * inv) * p.z;
        }
        const int cnt = min(64, end - kb);
        for (int j = 0; j < cnt; j += 4) {
            const int   jj = j + g;
            const int   oj = __shfl(o,  jj, 64);
            const float wj = __shfl(wt, jj, 64);
            float4 m = msg4[((size_t)oj << 4) + q];
            acc.x += wj * m.x;
            acc.y += wj * m.y;
            acc.z += wj * m.z;
            acc.w += wj * m.w;
        }
    }

#pragma unroll
    for (int d = 16; d < 64; d <<= 1) {
        acc.x += __shfl_xor(acc.x, d, 64);
        acc.y += __shfl_xor(acc.y, d, 64);
        acc.z += __shfl_xor(acc.z, d, 64);
        acc.w += __shfl_xor(acc.w, d, 64);
    }
    if (g == 0) ((float4*)out)[((size_t)wave << 4) + q] = acc;
}

// ---------------------------------------------------------------------------
extern "C" void kernel_launch(void* const* d_in, const int* in_sizes, int n_in,
                              void* d_out, int out_size, void* d_ws, size_t ws_size,
                              hipStream_t stream) {
    const float* x_source = (const float*)d_in[0];
    const float* x_target = (const float*)d_in[1];
    const float* nbhd     = (const float*)d_in[2];
    const float* w_s      = (const float*)d_in[3];
    const float* w_t      = (const float*)d_in[4];
    const float* att      = (const float*)d_in[5];
    const int*   row_idx  = (const int*)d_in[6];
    const int*   col_idx  = (const int*)d_in[7];

    const int n_s = in_sizes[0] / D_IN;   // 100000
    const int n_t = in_sizes[1] / D_IN;   // 20000
    const int nnz = in_sizes[2];          // 2000000

    float* out = (float*)d_out;
    float* mos = out;                          // (n_s, 64)
    float* mot = out + (size_t)n_s * D_OUT;    // (n_t, 64)

    // common workspace head
    char* ws = (char*)d_ws;
    float* s_msg   = (float*)ws;  ws += sizeof(float) * (size_t)n_s * D_OUT;
    float* t_msg   = (float*)ws;  ws += sizeof(float) * (size_t)n_t * D_OUT;
    float* s_score = (float*)ws;  ws += sizeof(float) * (size_t)n_s;
    float* t_score = (float*)ws;  ws += sizeof(float) * (size_t)n_t;

    // R13 grouped-sort tail
    const int NBCH = (nnz + CHUNK - 1) / CHUNK;          // 652
    const int NGR  = (n_t + (1 << GS_R) - 1) >> GS_R;    // 625
    const int NGC  = (n_s + (1 << GS_C) - 1) >> GS_C;    // 782
    char* wsb = ws;
    int* cntR  = (int*)wsb;  wsb += sizeof(int) * (size_t)NBCH * NGR;
    int* cntC  = (int*)wsb;  wsb += sizeof(int) * (size_t)NBCH * NGC;
    int* gposR = (int*)wsb;  wsb += sizeof(int) * (size_t)NGR * NBCH;
    int* gposC = (int*)wsb;  wsb += sizeof(int) * (size_t)NGC * NBCH;
    int* gtotR = (int*)wsb;  wsb += sizeof(int) * (size_t)NGR;
    int* goffR = (int*)wsb;  wsb += sizeof(int) * (size_t)(NGR + 1);
    int* gtotC = (int*)wsb;  wsb += sizeof(int) * (size_t)NGC;
    int* goffC = (int*)wsb;  wsb += sizeof(int) * (size_t)(NGC + 1);
    int* koffR = (int*)wsb;  wsb += sizeof(int) * (size_t)NGR * ((1 << GS_R) + 1);
    int* koffC = (int*)wsb;  wsb += sizeof(int) * (size_t)NGC * ((1 << GS_C) + 1);
    wsb = (char*)(((uintptr_t)wsb + 15) & ~(uintptr_t)15);
    float4* pay_r = (float4*)wsb;  wsb += sizeof(float4) * (size_t)nnz;
    float4* pay_c = (float4*)wsb;  wsb += sizeof(float4) * (size_t)nnz;
    const size_t need_sort = (size_t)(wsb - (char*)d_ws);

    // 1) messages + scores (bitwise-stable path)
    msg_score8_kernel<<<(n_s + RPB - 1) / RPB, 256, 0, stream>>>(
        x_source, w_s, att, 0, s_msg, s_score, n_s);
    msg_score8_kernel<<<(n_t + RPB - 1) / RPB, 256, 0, stream>>>(
        x_target, w_t, att, D_OUT, t_msg, t_score, n_t);

    if (ws_size >= need_sort) {
        // ---------------- R13 grouped-sort path ----------------
        khist2_kernel<<<NBCH, 256, (size_t)(NGR + NGC) * 4, stream>>>(
            row_idx, col_idx, cntR, cntC, nnz, NGR, NGC);

        kgsum_kernel<<<NGR, 256, 0, stream>>>(cntR, gtotR, NBCH, NGR);
        kgsum_kernel<<<NGC, 256, 0, stream>>>(cntC, gtotC, NBCH, NGC);
        kgscan2_kernel<<<2, 1024, 0, stream>>>(gtotR, goffR, NGR, gtotC, goffC, NGC);
        kgpos_kernel<<<NGR, 256, 0, stream>>>(cntR, goffR, gposR, NBCH, NGR);
        kgpos_kernel<<<NGC, 256, 0, stream>>>(cntC, goffC, gposC, NBCH, NGC);

        const size_t smem_part = (size_t)CHUNK * 16 + (size_t)(3 * (NGC + 1)) * 4;
        kpart3_kernel<<<NBCH, 256, smem_part, stream>>>(
            row_idx, col_idx, nbhd, s_score, t_score,
            gposR, gposC, pay_r, pay_c, nnz, NBCH, NGR, NGC);

        const size_t smem_s_r = (size_t)CAPB_R * 14 + (size_t)(3 * (1 << GS_R) + 2) * 4;
        const size_t smem_s_c = (size_t)CAPB_C * 14 + (size_t)(3 * (1 << GS_C) + 2) * 4;
        ksort_kernel<<<NGR, 512, smem_s_r, stream>>>(
            pay_r, goffR, koffR, 1 << GS_R, CAPB_R);
        ksort_kernel<<<NGC, 512, smem_s_c, stream>>>(
            pay_c, goffC, koffC, 1 << GS_C, CAPB_C);

        kaccum2_kernel<<<(int)(((size_t)n_t * 64 + 255) / 256), 256, 0, stream>>>(
            koffR, GS_R, pay_r, s_msg, mot, n_t);
        kaccum2_kernel<<<(int)(((size_t)n_s * 64 + 255) / 256), 256, 0, stream>>>(
            koffC, GS_C, pay_c, t_msg, mos, n_s);
    } else {
        // ---------------- fallback: R7 hist+scan+sort path ----------------
        const int col_base = n_t * SUB;
        const int n_cnt    = (n_t + n_s) * SUB;
        const int total    = 2 * nnz;

        char* wsf = ws;
        int* cnt  = (int*)wsf;  wsf += sizeof(int) * (size_t)n_cnt;
        int* cur  = (int*)wsf;  wsf += sizeof(int) * (size_t)n_cnt;
        int* off  = (int*)wsf;  wsf += sizeof(int) * (size_t)(n_cnt + 1);
        int* bsum = (int*)wsf;  wsf += sizeof(int) * 1024;
        wsf = (char*)(((uintptr_t)wsf + 15) & ~(uintptr_t)15);
        float4* pay = (float4*)wsf;

        hipMemsetAsync(cnt, 0, sizeof(int) * (size_t)n_cnt, stream);

        hist_kernel<<<(nnz + 255) / 256, 256, 0, stream>>>(
            row_idx, col_idx, cnt, col_base, nnz);

        const int nb = (n_cnt + SCAN_CHUNK - 1) / SCAN_CHUNK;
        scan_stage1<<<nb, 256, 0, stream>>>(cnt, bsum, n_cnt);
        scan_stage2<<<1, 1024, 0, stream>>>(bsum, nb);
        scan_stage3<<<nb, 256, 0, stream>>>(cnt, bsum, off, cur, n_cnt, total);

        scatter_row_kernel<<<(nnz + 255) / 256, 256, 0, stream>>>(
            row_idx, col_idx, nbhd, s_score, t_score, cur, pay, nnz);
        scatter_col_kernel<<<(nnz + 255) / 256, 256, 0, stream>>>(
            row_idx, col_idx, nbhd, s_score, t_score, cur, col_base, pay, nnz);

        accum_kernel<<<(int)(((size_t)n_t * 64 + 255) / 256), 256, 0, stream>>>(
            off, 0, pay, s_msg, mot, n_t);
        accum_kernel<<<(int)(((size_t)n_s * 64 + 255) / 256), 256, 0, stream>>>(
            off, col_base, pay, t_msg, mos, n_s);
    }
}

// Round 8
// 483.366 us; speedup vs baseline: 1.4108x; 1.0951x over previous
//
#include <hip/hip_runtime.h>
#include <stdint.h>

#define D_IN  128
#define D_OUT 64
#define NEG_SLOPE 0.2f
#define SUB       8      // (fallback path) sub-bins per key
#define SUB_SHIFT 3
#define SCAN_CHUNK 4096
#define RPW       8      // rows per wave in msg_score8
#define RPB       32     // rows per block

// ---- R14 grouped-sort path ----
#define CHUNK   2048     // edges per chunk (sp = 32KB -> 3 blocks/CU)
#define GS_R    5        // rows: group = r>>5  -> 625 groups of 32 keys
#define GS_C    7        // cols: group = c>>7  -> 782 groups of 128 keys
#define CAPB_R  3712     // per row-group capacity (mean 3200, +9 sigma)
#define CAPB_C  3072     // per col-group capacity (mean 2560, +10 sigma)

// ---------------------------------------------------------------------------
// Fused skinny GEMM + attention score, 8 rows per wave, x staged in LDS.
// NUMERICS ARE BITWISE-IDENTICAL to the R4/R6/R7 passing path (absmax=128).
// DO NOT reassociate (R5 failed at 768 from an algebraically-equal variant).
// ---------------------------------------------------------------------------
__global__ void msg_score8_kernel(const float* __restrict__ x,
                                  const float* __restrict__ w,
                                  const float* __restrict__ att, int att_off,
                                  float* __restrict__ msg,
                                  float* __restrict__ score,
                                  int n_rows) {
    __shared__ float wl[D_IN * D_OUT];           // 32 KB
    __shared__ float xs[RPB * D_IN];             // 16 KB
    const int tid = threadIdx.x;

    const float4* w4  = (const float4*)w;
    float4*       wl4 = (float4*)wl;
#pragma unroll
    for (int i = 0; i < 8; ++i) wl4[tid + i * 256] = w4[tid + i * 256];

    const int rb = blockIdx.x * RPB;
    float4* xs4 = (float4*)xs;
    const float4* x4 = (const float4*)x;
#pragma unroll
    for (int i = 0; i < 4; ++i) {
        const int f  = tid + i * 256;
        const int r  = f >> 5;
        const int k4 = f & 31;
        const int row = min(rb + r, n_rows - 1);
        xs4[f] = x4[(size_t)row * 32 + k4];
    }
    __syncthreads();

    const int wv = tid >> 6;
    const int j  = tid & 63;
    const int rl = wv * RPW;
    const float4* xw = (const float4*)(xs + rl * D_IN);

    float acc[RPW];
#pragma unroll
    for (int r = 0; r < RPW; ++r) acc[r] = 0.f;

#pragma unroll 2
    for (int k4 = 0; k4 < D_IN / 4; ++k4) {
        const float w0 = wl[(k4 * 4 + 0) * D_OUT + j];
        const float w1 = wl[(k4 * 4 + 1) * D_OUT + j];
        const float w2 = wl[(k4 * 4 + 2) * D_OUT + j];
        const float w3 = wl[(k4 * 4 + 3) * D_OUT + j];
#pragma unroll
        for (int r = 0; r < RPW; ++r) {
            const float4 xv = xw[r * 32 + k4];
            acc[r] += xv.x * w0;
            acc[r] += xv.y * w1;
            acc[r] += xv.z * w2;
            acc[r] += xv.w * w3;
        }
    }

    const float aj = att[att_off + j];
#pragma unroll
    for (int r = 0; r < RPW; ++r) {
        const int row = rb + rl + r;
        if (row < n_rows) msg[(size_t)row * D_OUT + j] = acc[r];
        float v = acc[r] * aj;
#pragma unroll
        for (int off = 32; off > 0; off >>= 1) v += __shfl_down(v, off, 64);
        if (j == 0 && row < n_rows) score[row] = v;
    }
}

// ---------------------------------------------------------------------------
// Stage 1 (kept): per-chunk histograms for both directions in one pass.
// ---------------------------------------------------------------------------
__global__ void __launch_bounds__(256)
khist2_kernel(const int* __restrict__ row_idx, const int* __restrict__ col_idx,
              int* __restrict__ cntR, int* __restrict__ cntC,
              int nnz, int ngr, int ngc) {
    extern __shared__ int hs[];
    int* hr = hs;
    int* hc = hs + ngr;
    const int tid  = threadIdx.x;
    const int base = blockIdx.x * CHUNK;
    const int lim  = min(CHUNK, nnz - base);

    for (int k = tid; k < ngr + ngc; k += 256) hs[k] = 0;
    __syncthreads();
    for (int k = tid; k < lim; k += 256) {
        atomicAdd(&hr[row_idx[base + k] >> GS_R], 1);
        atomicAdd(&hc[col_idx[base + k] >> GS_C], 1);
    }
    __syncthreads();
    for (int g = tid; g < ngr; g += 256) cntR[(size_t)blockIdx.x * ngr + g] = hr[g];
    for (int g = tid; g < ngc; g += 256) cntC[(size_t)blockIdx.x * ngc + g] = hc[g];
}

__global__ void __launch_bounds__(256)
kgsum_kernel(const int* __restrict__ cnt, int* __restrict__ gtot,
             int NB, int ng) {
    __shared__ int lds[256];
    const int g = blockIdx.x;
    const int t = threadIdx.x;
    int s = 0;
    for (int b = t; b < NB; b += 256) s += cnt[(size_t)b * ng + g];
    lds[t] = s;
    __syncthreads();
    for (int d = 128; d > 0; d >>= 1) {
        if (t < d) lds[t] += lds[t + d];
        __syncthreads();
    }
    if (t == 0) gtot[g] = lds[0];
}

__global__ void __launch_bounds__(1024)
kgscan2_kernel(const int* __restrict__ gtotR, int* __restrict__ goffR, int ngr,
               const int* __restrict__ gtotC, int* __restrict__ goffC, int ngc) {
    __shared__ int lds[1024];
    const int t = threadIdx.x;
    const int* gt = blockIdx.x ? gtotC : gtotR;
    int*       go = blockIdx.x ? goffC : goffR;
    const int  n  = blockIdx.x ? ngc : ngr;
    const int v = (t < n) ? gt[t] : 0;
    lds[t] = v;
    __syncthreads();
    for (int d = 1; d < 1024; d <<= 1) {
        int u = (t >= d) ? lds[t - d] : 0;
        __syncthreads();
        lds[t] += u;
        __syncthreads();
    }
    if (t < n) go[t] = lds[t] - v;
    if (t == n - 1) go[n] = lds[t];
}

// 4 items/thread -> supports NB up to 1024 (NBCH = 977 at CHUNK=2048)
__global__ void __launch_bounds__(256)
kgpos_kernel(const int* __restrict__ cnt, const int* __restrict__ goff,
             int* __restrict__ gpos, int NB, int ng) {
    __shared__ int lds[256];
    const int g = blockIdx.x;
    const int t = threadIdx.x;
    int c[4];
    int s = 0;
#pragma unroll
    for (int u = 0; u < 4; ++u) {
        const int b = 4 * t + u;
        c[u] = (b < NB) ? cnt[(size_t)b * ng + g] : 0;
        s += c[u];
    }
    lds[t] = s;
    __syncthreads();
    for (int d = 1; d < 256; d <<= 1) {
        int u = (t >= d) ? lds[t - d] : 0;
        __syncthreads();
        lds[t] += u;
        __syncthreads();
    }
    int ex = goff[g] + lds[t] - s;
#pragma unroll
    for (int u = 0; u < 4; ++u) {
        const int b = 4 * t + u;
        if (b < NB) { gpos[(size_t)g * NB + b] = ex; ex += c[u]; }
    }
}

// ---------------------------------------------------------------------------
// R14 stage 3: chunk-local LDS counting sort + grouped global write.
// Changes vs R13 (which was latency-bound at 9.5% occupancy, 158 us):
//  - serial tid==0 prefix scan (626/783 dependent LDS RMWs, x2 dirs) ->
//    256-thread Hillis-Steele scan (scratch reuses gofb before its load)
//  - no register staging (VGPR 136 -> ~60); each direction re-reads its
//    indices/scores (per-block slices are L1/L2-hot)
//  - CHUNK 3072 -> 2048: LDS 58.5 -> ~41 KB -> 3 blocks/CU, 977 blocks
// Entry format, e expression, and group segment content are IDENTICAL to
// R13 (only intra-segment arrival order changes - already nondeterministic).
// ---------------------------------------------------------------------------
__global__ void __launch_bounds__(256)
kpart3_kernel(const int* __restrict__ row_idx,
              const int* __restrict__ col_idx,
              const float* __restrict__ nbhd,
              const float* __restrict__ s_score,
              const float* __restrict__ t_score,
              const int* __restrict__ gposR, const int* __restrict__ gposC,
              float4* __restrict__ pay_r, float4* __restrict__ pay_c,
              int nnz, int NB, int ngr, int ngc) {
    extern __shared__ char sm[];
    float4* sp   = (float4*)sm;                      // CHUNK entries (32KB)
    int*    cnt  = (int*)(sm + (size_t)CHUNK * 16);  // ngc+1
    int*    off  = cnt + (ngc + 1);                  // ngc+1
    int*    gofb = off + (ngc + 1);                  // ngc (scan scratch first)

    const int tid  = threadIdx.x;
    const int b    = blockIdx.x;
    const int base = b * CHUNK;
    const int lim  = min(CHUNK, nnz - base);

#pragma unroll 1
    for (int d = 0; d < 2; ++d) {
        const int gs   = d ? GS_C : GS_R;
        const int ng   = d ? ngc : ngr;
        const int mask = (1 << gs) - 1;
        const int* kidx = d ? col_idx : row_idx;
        const int* oidx = d ? row_idx : col_idx;
        const int* gp  = d ? gposC : gposR;
        float4*    pd  = d ? pay_c : pay_r;

        for (int k = tid; k <= ng; k += 256) cnt[k] = 0;
        __syncthreads();

        // histogram of coarse groups
        for (int k = tid; k < lim; k += 256)
            atomicAdd(&cnt[kidx[base + k] >> gs], 1);
        __syncthreads();

        // parallel exclusive scan of cnt[0..ng] (scratch = gofb[0..255])
        const int ipt = (ng + 1 + 255) >> 8;   // items/thread: 3 (row), 4 (col)
        int c4[4];
        int s = 0;
#pragma unroll
        for (int u = 0; u < 4; ++u) {
            const int k = tid * ipt + u;
            c4[u] = (u < ipt && k <= ng) ? cnt[k] : 0;
            s += c4[u];
        }
        gofb[tid] = s;
        __syncthreads();
        for (int dd = 1; dd < 256; dd <<= 1) {
            const int uu = (tid >= dd) ? gofb[tid - dd] : 0;
            __syncthreads();
            gofb[tid] += uu;
            __syncthreads();
        }
        int ex = gofb[tid] - s;
        __syncthreads();                        // gofb reads done; safe to reuse
#pragma unroll
        for (int u = 0; u < 4; ++u) {
            const int k = tid * ipt + u;
            if (u < ipt && k <= ng) { off[k] = ex; cnt[k] = ex; ex += c4[u]; }
        }
        __syncthreads();

        // prestage global positions + scatter entries into LDS
        for (int k = tid; k < ng; k += 256) gofb[k] = gp[(size_t)k * NB + b];
        for (int k = tid; k < lim; k += 256) {
            const int key = kidx[base + k];
            const int oth = oidx[base + k];
            const int r   = d ? oth : key;
            const int c   = d ? key : oth;
            const float xv = s_score[c] + t_score[r];
            const float e  = xv >= 0.f ? xv : NEG_SLOPE * xv;
            const int grp = key >> gs;
            const int pos = atomicAdd(&cnt[grp], 1);
            sp[pos] = make_float4(__int_as_float(oth | ((key & mask) << 20)),
                                  e, nbhd[base + k], __int_as_float(grp));
        }
        __syncthreads();

        // grouped write: consecutive k within a segment -> consecutive dst
        for (int k = tid; k < lim; k += 256) {
            const float4 p = sp[k];
            const int grp = __float_as_int(p.w);
            pd[(size_t)gofb[grp] + (k - off[grp])] = p;
        }
        __syncthreads();
    }
}

// ---------------------------------------------------------------------------
// Stage 4 (kept): IN-PLACE per-group key sort. Dense read -> LDS SoA +
// histogram -> 16-bit perm -> dense sorted writeback + per-key offsets koff.
// ---------------------------------------------------------------------------
__global__ void __launch_bounds__(512)
ksort_kernel(float4* __restrict__ pay,
             const int* __restrict__ goff,
             int* __restrict__ koff,
             int kpg, int cap) {
    extern __shared__ char sm[];
    int*    PO   = (int*)sm;                                  // cap
    float*  E    = (float*)(sm + (size_t)cap * 4);            // cap
    float*  B    = (float*)(sm + (size_t)cap * 8);            // cap
    unsigned short* perm = (unsigned short*)(sm + (size_t)cap * 12); // cap
    int*    scnt = (int*)(sm + (size_t)cap * 14);             // kpg
    int*    soff = scnt + kpg;                                // kpg+1
    int*    scur = soff + kpg + 1;                            // kpg

    const int g    = blockIdx.x;
    const int tid  = threadIdx.x;
    const int mask = kpg - 1;

    const int beg = goff[g];
    const int n   = min(goff[g + 1] - beg, cap);

    for (int k = tid; k < kpg; k += 512) scnt[k] = 0;
    __syncthreads();

    for (int k = tid; k < n; k += 512) {
        const float4 p = pay[(size_t)beg + k];
        const int pk = __float_as_int(p.x);
        PO[k] = pk; E[k] = p.y; B[k] = p.z;
        atomicAdd(&scnt[(pk >> 20) & mask], 1);
    }
    __syncthreads();

    if (tid == 0) {
        int a = 0;
        for (int k = 0; k < kpg; ++k) { const int t = scnt[k]; soff[k] = a; scur[k] = a; a += t; }
        soff[kpg] = a;
    }
    __syncthreads();

    for (int k = tid; k < n; k += 512)
        perm[atomicAdd(&scur[(PO[k] >> 20) & mask], 1)] = (unsigned short)k;
    __syncthreads();

    // sorted dense writeback (all reads done before this point -> in-place ok)
    for (int k = tid; k < n; k += 512) {
        const int kk = perm[k];
        pay[(size_t)beg + k] = make_float4(__int_as_float(PO[kk]), E[kk], B[kk], 0.f);
    }
    for (int k = tid; k <= kpg; k += 512)
        koff[(size_t)g * (kpg + 1) + k] = beg + soff[k];
}

// ---------------------------------------------------------------------------
// Stage 5 (kept): VERBATIM wave-per-key accum (f64 ers, same weight formula,
// 16-lane gather + butterfly), LDS-free, dense contiguous per-key segments.
// ---------------------------------------------------------------------------
__global__ void kaccum2_kernel(const int* __restrict__ koff, int kshift,
                               const float4* __restrict__ pay,
                               const float* __restrict__ other_msg,
                               float* __restrict__ out, int n_mine) {
    const int wave = (int)((blockIdx.x * (size_t)blockDim.x + threadIdx.x) >> 6);
    const int lane = threadIdx.x & 63;
    if (wave >= n_mine) return;

    const int kpg = 1 << kshift;
    const int grp = wave >> kshift;
    const int jk  = wave & (kpg - 1);
    const int beg = koff[(size_t)grp * (kpg + 1) + jk];
    const int end = koff[(size_t)grp * (kpg + 1) + jk + 1];

    double psum = 0.0;
    for (int k = beg + lane; k < end; k += 64) psum += (double)pay[k].y;
#pragma unroll
    for (int o = 32; o > 0; o >>= 1) psum += __shfl_down(psum, o, 64);
    double ers = __shfl(psum, 0, 64);
    if (ers == 0.0) ers = 1.0;
    const double inv = 1.0 / ers;

    const int g = lane >> 4;
    const int q = lane & 15;
    const float4* msg4 = (const float4*)other_msg;
    float4 acc = make_float4(0.f, 0.f, 0.f, 0.f);

    for (int kb = beg; kb < end; kb += 64) {
        const int k = kb + lane;
        int o = 0; float wt = 0.f;
        if (k < end) {
            float4 p = pay[k];
            o  = __float_as_int(p.x) & 0xFFFFF;
            wt = (float)((double)p.y * inv) * p.z;
        }
        const int cnt = min(64, end - kb);
        for (int j = 0; j < cnt; j += 4) {
            const int   jj = j + g;
            const int   oj = __shfl(o,  jj, 64);
            const float wj = __shfl(wt, jj, 64);
            float4 m = msg4[((size_t)oj << 4) + q];
            acc.x += wj * m.x;
            acc.y += wj * m.y;
            acc.z += wj * m.z;
            acc.w += wj * m.w;
        }
    }

#pragma unroll
    for (int d = 16; d < 64; d <<= 1) {
        acc.x += __shfl_xor(acc.x, d, 64);
        acc.y += __shfl_xor(acc.y, d, 64);
        acc.z += __shfl_xor(acc.z, d, 64);
        acc.w += __shfl_xor(acc.w, d, 64);
    }
    if (g == 0) ((float4*)out)[((size_t)wave << 4) + q] = acc;
}

// ===========================================================================
// FALLBACK PATH (R7, proven): hist -> scan -> per-direction scatter -> accum.
// Used only if ws_size can't hold the sort-path payload (~102 MB).
// ===========================================================================
__global__ void hist_kernel(const int* __restrict__ row_idx,
                            const int* __restrict__ col_idx,
                            int* __restrict__ cnt, int col_base, int nnz) {
    const int i = blockIdx.x * blockDim.x + threadIdx.x;
    if (i >= nnz) return;
    const int s = i & (SUB - 1);
    atomicAdd(&cnt[(row_idx[i] << SUB_SHIFT) + s], 1);
    atomicAdd(&cnt[col_base + (col_idx[i] << SUB_SHIFT) + s], 1);
}

__global__ void scan_stage1(const int* __restrict__ cnt, int* __restrict__ bsum,
                            int n) {
    __shared__ int lds[256];
    const int t = threadIdx.x;
    const int base = blockIdx.x * SCAN_CHUNK;
    int s = 0;
    for (int k = t; k < SCAN_CHUNK; k += 256) {
        const int j = base + k;
        if (j < n) s += cnt[j];
    }
    lds[t] = s;
    __syncthreads();
    for (int d = 128; d > 0; d >>= 1) {
        if (t < d) lds[t] += lds[t + d];
        __syncthreads();
    }
    if (t == 0) bsum[blockIdx.x] = lds[0];
}

__global__ void scan_stage2(int* __restrict__ bsum, int nb) {
    __shared__ int lds[1024];
    const int t = threadIdx.x;
    const int v = (t < nb) ? bsum[t] : 0;
    lds[t] = v;
    __syncthreads();
    for (int d = 1; d < 1024; d <<= 1) {
        int u = (t >= d) ? lds[t - d] : 0;
        __syncthreads();
        lds[t] += u;
        __syncthreads();
    }
    if (t < nb) bsum[t] = lds[t] - v;
}

__global__ void scan_stage3(const int* __restrict__ cnt,
                            const int* __restrict__ bsum,
                            int* __restrict__ off, int* __restrict__ cur,
                            int n, int total) {
    __shared__ int lds[256];
    const int t = threadIdx.x;
    const int base = blockIdx.x * SCAN_CHUNK + t * 16;
    int c[16];
    int s = 0;
#pragma unroll
    for (int k = 0; k < 16; ++k) {
        const int j = base + k;
        c[k] = (j < n) ? cnt[j] : 0;
        s += c[k];
    }
    lds[t] = s;
    __syncthreads();
    for (int d = 1; d < 256; d <<= 1) {
        int u = (t >= d) ? lds[t - d] : 0;
        __syncthreads();
        lds[t] += u;
        __syncthreads();
    }
    int ex = bsum[blockIdx.x] + lds[t] - s;
#pragma unroll
    for (int k = 0; k < 16; ++k) {
        const int j = base + k;
        if (j < n) { off[j] = ex; cur[j] = ex; ex += c[k]; }
    }
    if (blockIdx.x == 0 && t == 0) off[n] = total;
}

__global__ void scatter_row_kernel(const int* __restrict__ row_idx,
                                   const int* __restrict__ col_idx,
                                   const float* __restrict__ nbhd,
                                   const float* __restrict__ s_score,
                                   const float* __restrict__ t_score,
                                   int* __restrict__ cur,
                                   float4* __restrict__ pay, int nnz) {
    const int i = blockIdx.x * blockDim.x + threadIdx.x;
    if (i >= nnz) return;
    const int r = row_idx[i];
    const int c = col_idx[i];
    const float xv = s_score[c] + t_score[r];
    const float e  = xv >= 0.f ? xv : NEG_SLOPE * xv;
    const int p = atomicAdd(&cur[(r << SUB_SHIFT) + (i & (SUB - 1))], 1);
    pay[p] = make_float4(__int_as_float(c), e, nbhd[i], 0.f);
}

__global__ void scatter_col_kernel(const int* __restrict__ row_idx,
                                   const int* __restrict__ col_idx,
                                   const float* __restrict__ nbhd,
                                   const float* __restrict__ s_score,
                                   const float* __restrict__ t_score,
                                   int* __restrict__ cur, int col_base,
                                   float4* __restrict__ pay, int nnz) {
    const int i = blockIdx.x * blockDim.x + threadIdx.x;
    if (i >= nnz) return;
    const int r = row_idx[i];
    const int c = col_idx[i];
    const float xv = s_score[c] + t_score[r];
    const float e  = xv >= 0.f ? xv : NEG_SLOPE * xv;
    const int p = atomicAdd(&cur[col_base + (c << SUB_SHIFT) + (i & (SUB - 1))], 1);
    pay[p] = make_float4(__int_as_float(r), e, nbhd[i], 0.f);
}

__global__ void accum_kernel(const int* __restrict__ off, int off_base,
                             const float4* __restrict__ pay,
                             const float* __restrict__ other_msg,
                             float* __restrict__ out, int n_mine) {
    const int wave = (int)((blockIdx.x * (size_t)blockDim.x + threadIdx.x) >> 6);
    const int lane = threadIdx.x & 63;
    if (wave >= n_mine) return;

    const int beg = off[off_base + (wave << SUB_SHIFT)];
    const int end = off[off_base + (wave << SUB_SHIFT) + SUB];

    double psum = 0.0;
    for (int k = beg + lane; k < end; k += 64) psum += (double)pay[k].y;
#pragma unroll
    for (int o = 32; o > 0; o >>= 1) psum += __shfl_down(psum, o, 64);
    double ers = __shfl(psum, 0, 64);
    if (ers == 0.0) ers = 1.0;
    const double inv = 1.0 / ers;

    const int g = lane >> 4;
    const int q = lane & 15;
    const float4* msg4 = (const float4*)other_msg;
    float4 acc = make_float4(0.f, 0.f, 0.f, 0.f);

    for (int kb = beg; kb < end; kb += 64) {
        const int k = kb + lane;
        int o = 0; float wt = 0.f;
        if (k < end) {
            float4 p = pay[k];
            o  = __float_as_int(p.x);
            wt = (float)((double)p.y * inv) * p.z;
        }
        const int cnt = min(64, end - kb);
        for (int j = 0; j < cnt; j += 4) {
            const int   jj = j + g;
            const int   oj = __shfl(o,  jj, 64);
            const float wj = __shfl(wt, jj, 64);
            float4 m = msg4[((size_t)oj << 4) + q];
            acc.x += wj * m.x;
            acc.y += wj * m.y;
            acc.z += wj * m.z;
            acc.w += wj * m.w;
        }
    }

#pragma unroll
    for (int d = 16; d < 64; d <<= 1) {
        acc.x += __shfl_xor(acc.x, d, 64);
        acc.y += __shfl_xor(acc.y, d, 64);
        acc.z += __shfl_xor(acc.z, d, 64);
        acc.w += __shfl_xor(acc.w, d, 64);
    }
    if (g == 0) ((float4*)out)[((size_t)wave << 4) + q] = acc;
}

// ---------------------------------------------------------------------------
extern "C" void kernel_launch(void* const* d_in, const int* in_sizes, int n_in,
                              void* d_out, int out_size, void* d_ws, size_t ws_size,
                              hipStream_t stream) {
    const float* x_source = (const float*)d_in[0];
    const float* x_target = (const float*)d_in[1];
    const float* nbhd     = (const float*)d_in[2];
    const float* w_s      = (const float*)d_in[3];
    const float* w_t      = (const float*)d_in[4];
    const float* att      = (const float*)d_in[5];
    const int*   row_idx  = (const int*)d_in[6];
    const int*   col_idx  = (const int*)d_in[7];

    const int n_s = in_sizes[0] / D_IN;   // 100000
    const int n_t = in_sizes[1] / D_IN;   // 20000
    const int nnz = in_sizes[2];          // 2000000

    float* out = (float*)d_out;
    float* mos = out;                          // (n_s, 64)
    float* mot = out + (size_t)n_s * D_OUT;    // (n_t, 64)

    // common workspace head
    char* ws = (char*)d_ws;
    float* s_msg   = (float*)ws;  ws += sizeof(float) * (size_t)n_s * D_OUT;
    float* t_msg   = (float*)ws;  ws += sizeof(float) * (size_t)n_t * D_OUT;
    float* s_score = (float*)ws;  ws += sizeof(float) * (size_t)n_s;
    float* t_score = (float*)ws;  ws += sizeof(float) * (size_t)n_t;

    // R14 grouped-sort tail
    const int NBCH = (nnz + CHUNK - 1) / CHUNK;          // 977
    const int NGR  = (n_t + (1 << GS_R) - 1) >> GS_R;    // 625
    const int NGC  = (n_s + (1 << GS_C) - 1) >> GS_C;    // 782
    char* wsb = ws;
    int* cntR  = (int*)wsb;  wsb += sizeof(int) * (size_t)NBCH * NGR;
    int* cntC  = (int*)wsb;  wsb += sizeof(int) * (size_t)NBCH * NGC;
    int* gposR = (int*)wsb;  wsb += sizeof(int) * (size_t)NGR * NBCH;
    int* gposC = (int*)wsb;  wsb += sizeof(int) * (size_t)NGC * NBCH;
    int* gtotR = (int*)wsb;  wsb += sizeof(int) * (size_t)NGR;
    int* goffR = (int*)wsb;  wsb += sizeof(int) * (size_t)(NGR + 1);
    int* gtotC = (int*)wsb;  wsb += sizeof(int) * (size_t)NGC;
    int* goffC = (int*)wsb;  wsb += sizeof(int) * (size_t)(NGC + 1);
    int* koffR = (int*)wsb;  wsb += sizeof(int) * (size_t)NGR * ((1 << GS_R) + 1);
    int* koffC = (int*)wsb;  wsb += sizeof(int) * (size_t)NGC * ((1 << GS_C) + 1);
    wsb = (char*)(((uintptr_t)wsb + 15) & ~(uintptr_t)15);
    float4* pay_r = (float4*)wsb;  wsb += sizeof(float4) * (size_t)nnz;
    float4* pay_c = (float4*)wsb;  wsb += sizeof(float4) * (size_t)nnz;
    const size_t need_sort = (size_t)(wsb - (char*)d_ws);

    // 1) messages + scores (bitwise-stable path)
    msg_score8_kernel<<<(n_s + RPB - 1) / RPB, 256, 0, stream>>>(
        x_source, w_s, att, 0, s_msg, s_score, n_s);
    msg_score8_kernel<<<(n_t + RPB - 1) / RPB, 256, 0, stream>>>(
        x_target, w_t, att, D_OUT, t_msg, t_score, n_t);

    if (ws_size >= need_sort) {
        // ---------------- R14 grouped-sort path ----------------
        khist2_kernel<<<NBCH, 256, (size_t)(NGR + NGC) * 4, stream>>>(
            row_idx, col_idx, cntR, cntC, nnz, NGR, NGC);

        kgsum_kernel<<<NGR, 256, 0, stream>>>(cntR, gtotR, NBCH, NGR);
        kgsum_kernel<<<NGC, 256, 0, stream>>>(cntC, gtotC, NBCH, NGC);
        kgscan2_kernel<<<2, 1024, 0, stream>>>(gtotR, goffR, NGR, gtotC, goffC, NGC);
        kgpos_kernel<<<NGR, 256, 0, stream>>>(cntR, goffR, gposR, NBCH, NGR);
        kgpos_kernel<<<NGC, 256, 0, stream>>>(cntC, goffC, gposC, NBCH, NGC);

        const size_t smem_part = (size_t)CHUNK * 16 + (size_t)(3 * NGC + 2) * 4;
        kpart3_kernel<<<NBCH, 256, smem_part, stream>>>(
            row_idx, col_idx, nbhd, s_score, t_score,
            gposR, gposC, pay_r, pay_c, nnz, NBCH, NGR, NGC);

        const size_t smem_s_r = (size_t)CAPB_R * 14 + (size_t)(3 * (1 << GS_R) + 2) * 4;
        const size_t smem_s_c = (size_t)CAPB_C * 14 + (size_t)(3 * (1 << GS_C) + 2) * 4;
        ksort_kernel<<<NGR, 512, smem_s_r, stream>>>(
            pay_r, goffR, koffR, 1 << GS_R, CAPB_R);
        ksort_kernel<<<NGC, 512, smem_s_c, stream>>>(
            pay_c, goffC, koffC, 1 << GS_C, CAPB_C);

        kaccum2_kernel<<<(int)(((size_t)n_t * 64 + 255) / 256), 256, 0, stream>>>(
            koffR, GS_R, pay_r, s_msg, mot, n_t);
        kaccum2_kernel<<<(int)(((size_t)n_s * 64 + 255) / 256), 256, 0, stream>>>(
            koffC, GS_C, pay_c, t_msg, mos, n_s);
    } else {
        // ---------------- fallback: R7 hist+scan+sort path ----------------
        const int col_base = n_t * SUB;
        const int n_cnt    = (n_t + n_s) * SUB;
        const int total    = 2 * nnz;

        char* wsf = ws;
        int* cnt  = (int*)wsf;  wsf += sizeof(int) * (size_t)n_cnt;
        int* cur  = (int*)wsf;  wsf += sizeof(int) * (size_t)n_cnt;
        int* off  = (int*)wsf;  wsf += sizeof(int) * (size_t)(n_cnt + 1);
        int* bsum = (int*)wsf;  wsf += sizeof(int) * 1024;
        wsf = (char*)(((uintptr_t)wsf + 15) & ~(uintptr_t)15);
        float4* pay = (float4*)wsf;

        hipMemsetAsync(cnt, 0, sizeof(int) * (size_t)n_cnt, stream);

        hist_kernel<<<(nnz + 255) / 256, 256, 0, stream>>>(
            row_idx, col_idx, cnt, col_base, nnz);

        const int nb = (n_cnt + SCAN_CHUNK - 1) / SCAN_CHUNK;
        scan_stage1<<<nb, 256, 0, stream>>>(cnt, bsum, n_cnt);
        scan_stage2<<<1, 1024, 0, stream>>>(bsum, nb);
        scan_stage3<<<nb, 256, 0, stream>>>(cnt, bsum, off, cur, n_cnt, total);

        scatter_row_kernel<<<(nnz + 255) / 256, 256, 0, stream>>>(
            row_idx, col_idx, nbhd, s_score, t_score, cur, pay, nnz);
        scatter_col_kernel<<<(nnz + 255) / 256, 256, 0, stream>>>(
            row_idx, col_idx, nbhd, s_score, t_score, cur, col_base, pay, nnz);

        accum_kernel<<<(int)(((size_t)n_t * 64 + 255) / 256), 256, 0, stream>>>(
            off, 0, pay, s_msg, mot, n_t);
        accum_kernel<<<(int)(((size_t)n_s * 64 + 255) / 256), 256, 0, stream>>>(
            off, col_base, pay, t_msg, mos, n_s);
    }
}

// Round 9
// 467.910 us; speedup vs baseline: 1.4574x; 1.0330x over previous
//
#include <hip/hip_runtime.h>
#include <stdint.h>

#define D_IN  128
#define D_OUT 64
#define NEG_SLOPE 0.2f
#define SUB       8      // (fallback path) sub-bins per key
#define SUB_SHIFT 3
#define SCAN_CHUNK 4096
#define RPW       8      // rows per wave in msg_score8
#define RPB       32     // rows per block

// ---- R15 grouped-sort path ----
#define CHUNK   2048     // edges per chunk
#define GS_R    5        // rows: group = r>>5  -> 625 groups of 32 keys
#define GS_C    7        // cols: group = c>>7  -> 782 groups of 128 keys
#define CAPB_R  3712     // per row-group capacity (mean 3200, +9 sigma)
#define CAPB_C  3072     // per col-group capacity (mean 2560, +10 sigma)

// ---------------------------------------------------------------------------
// Fused skinny GEMM + attention score, 8 rows per wave, x staged in LDS.
// NUMERICS ARE BITWISE-IDENTICAL to the R4/R6/R7 passing path (absmax=128).
// DO NOT reassociate (R5 failed at 768 from an algebraically-equal variant).
// ---------------------------------------------------------------------------
__global__ void msg_score8_kernel(const float* __restrict__ x,
                                  const float* __restrict__ w,
                                  const float* __restrict__ att, int att_off,
                                  float* __restrict__ msg,
                                  float* __restrict__ score,
                                  int n_rows) {
    __shared__ float wl[D_IN * D_OUT];           // 32 KB
    __shared__ float xs[RPB * D_IN];             // 16 KB
    const int tid = threadIdx.x;

    const float4* w4  = (const float4*)w;
    float4*       wl4 = (float4*)wl;
#pragma unroll
    for (int i = 0; i < 8; ++i) wl4[tid + i * 256] = w4[tid + i * 256];

    const int rb = blockIdx.x * RPB;
    float4* xs4 = (float4*)xs;
    const float4* x4 = (const float4*)x;
#pragma unroll
    for (int i = 0; i < 4; ++i) {
        const int f  = tid + i * 256;
        const int r  = f >> 5;
        const int k4 = f & 31;
        const int row = min(rb + r, n_rows - 1);
        xs4[f] = x4[(size_t)row * 32 + k4];
    }
    __syncthreads();

    const int wv = tid >> 6;
    const int j  = tid & 63;
    const int rl = wv * RPW;
    const float4* xw = (const float4*)(xs + rl * D_IN);

    float acc[RPW];
#pragma unroll
    for (int r = 0; r < RPW; ++r) acc[r] = 0.f;

#pragma unroll 2
    for (int k4 = 0; k4 < D_IN / 4; ++k4) {
        const float w0 = wl[(k4 * 4 + 0) * D_OUT + j];
        const float w1 = wl[(k4 * 4 + 1) * D_OUT + j];
        const float w2 = wl[(k4 * 4 + 2) * D_OUT + j];
        const float w3 = wl[(k4 * 4 + 3) * D_OUT + j];
#pragma unroll
        for (int r = 0; r < RPW; ++r) {
            const float4 xv = xw[r * 32 + k4];
            acc[r] += xv.x * w0;
            acc[r] += xv.y * w1;
            acc[r] += xv.z * w2;
            acc[r] += xv.w * w3;
        }
    }

    const float aj = att[att_off + j];
#pragma unroll
    for (int r = 0; r < RPW; ++r) {
        const int row = rb + rl + r;
        if (row < n_rows) msg[(size_t)row * D_OUT + j] = acc[r];
        float v = acc[r] * aj;
#pragma unroll
        for (int off = 32; off > 0; off >>= 1) v += __shfl_down(v, off, 64);
        if (j == 0 && row < n_rows) score[row] = v;
    }
}

// ---------------------------------------------------------------------------
// Stage 1 (kept): per-chunk histograms for both directions in one pass.
// ---------------------------------------------------------------------------
__global__ void __launch_bounds__(256)
khist2_kernel(const int* __restrict__ row_idx, const int* __restrict__ col_idx,
              int* __restrict__ cntR, int* __restrict__ cntC,
              int nnz, int ngr, int ngc) {
    extern __shared__ int hs[];
    int* hr = hs;
    int* hc = hs + ngr;
    const int tid  = threadIdx.x;
    const int base = blockIdx.x * CHUNK;
    const int lim  = min(CHUNK, nnz - base);

    for (int k = tid; k < ngr + ngc; k += 256) hs[k] = 0;
    __syncthreads();
    for (int k = tid; k < lim; k += 256) {
        atomicAdd(&hr[row_idx[base + k] >> GS_R], 1);
        atomicAdd(&hc[col_idx[base + k] >> GS_C], 1);
    }
    __syncthreads();
    for (int g = tid; g < ngr; g += 256) cntR[(size_t)blockIdx.x * ngr + g] = hr[g];
    for (int g = tid; g < ngc; g += 256) cntC[(size_t)blockIdx.x * ngc + g] = hc[g];
}

__global__ void __launch_bounds__(256)
kgsum_kernel(const int* __restrict__ cnt, int* __restrict__ gtot,
             int NB, int ng) {
    __shared__ int lds[256];
    const int g = blockIdx.x;
    const int t = threadIdx.x;
    int s = 0;
    for (int b = t; b < NB; b += 256) s += cnt[(size_t)b * ng + g];
    lds[t] = s;
    __syncthreads();
    for (int d = 128; d > 0; d >>= 1) {
        if (t < d) lds[t] += lds[t + d];
        __syncthreads();
    }
    if (t == 0) gtot[g] = lds[0];
}

__global__ void __launch_bounds__(1024)
kgscan2_kernel(const int* __restrict__ gtotR, int* __restrict__ goffR, int ngr,
               const int* __restrict__ gtotC, int* __restrict__ goffC, int ngc) {
    __shared__ int lds[1024];
    const int t = threadIdx.x;
    const int* gt = blockIdx.x ? gtotC : gtotR;
    int*       go = blockIdx.x ? goffC : goffR;
    const int  n  = blockIdx.x ? ngc : ngr;
    const int v = (t < n) ? gt[t] : 0;
    lds[t] = v;
    __syncthreads();
    for (int d = 1; d < 1024; d <<= 1) {
        int u = (t >= d) ? lds[t - d] : 0;
        __syncthreads();
        lds[t] += u;
        __syncthreads();
    }
    if (t < n) go[t] = lds[t] - v;
    if (t == n - 1) go[n] = lds[t];
}

// 4 items/thread -> supports NB up to 1024 (NBCH = 977 at CHUNK=2048)
__global__ void __launch_bounds__(256)
kgpos_kernel(const int* __restrict__ cnt, const int* __restrict__ goff,
             int* __restrict__ gpos, int NB, int ng) {
    __shared__ int lds[256];
    const int g = blockIdx.x;
    const int t = threadIdx.x;
    int c[4];
    int s = 0;
#pragma unroll
    for (int u = 0; u < 4; ++u) {
        const int b = 4 * t + u;
        c[u] = (b < NB) ? cnt[(size_t)b * ng + g] : 0;
        s += c[u];
    }
    lds[t] = s;
    __syncthreads();
    for (int d = 1; d < 256; d <<= 1) {
        int u = (t >= d) ? lds[t - d] : 0;
        __syncthreads();
        lds[t] += u;
        __syncthreads();
    }
    int ex = goff[g] + lds[t] - s;
#pragma unroll
    for (int u = 0; u < 4; ++u) {
        const int b = 4 * t + u;
        if (b < NB) { gpos[(size_t)g * NB + b] = ex; ex += c[u]; }
    }
}

// ---------------------------------------------------------------------------
// R15 stage 3: kpart4 — 2-BYTE TOKEN staging sort (vs R14's 16B float4 sp).
// R14 was latency-bound at 19.6% occupancy (42KB LDS -> 2-3 blocks/CU).
// Changes:
//  - counts loaded from khist2's cnt rows (coalesced; deletes re-histogram)
//  - staging sorts ushort tokens (edge index within chunk): sp = 4KB
//  - grouped-write phase re-reads kidx/oidx/nbhd[base+t] (L1/L2-hot 8KB
//    slices), computes e (bitwise-same expression), writes the IDENTICAL
//    piecewise-coalesced grouped pattern proven in R13/R14 (WRITE ~82MB).
// LDS 42KB -> ~13.5KB -> 8 blocks/CU (wave cap). Payload bytes identical;
// only intra-segment arrival order changes (already nondeterministic).
// ---------------------------------------------------------------------------
__global__ void __launch_bounds__(256)
kpart4_kernel(const int* __restrict__ row_idx,
              const int* __restrict__ col_idx,
              const float* __restrict__ nbhd,
              const float* __restrict__ s_score,
              const float* __restrict__ t_score,
              const int* __restrict__ cntR, const int* __restrict__ cntC,
              const int* __restrict__ gposR, const int* __restrict__ gposC,
              float4* __restrict__ pay_r, float4* __restrict__ pay_c,
              int nnz, int NB, int ngr, int ngc) {
    extern __shared__ char sm[];
    unsigned short* sp = (unsigned short*)sm;        // CHUNK tokens (4KB)
    int* cnt  = (int*)(sm + (size_t)CHUNK * 2);      // ngc+1 (cursors)
    int* off  = cnt + (ngc + 1);                     // ngc+1
    int* gofb = off + (ngc + 1);                     // ngc (scan scratch first)

    const int tid  = threadIdx.x;
    const int b    = blockIdx.x;
    const int base = b * CHUNK;
    const int lim  = min(CHUNK, nnz - base);

#pragma unroll 1
    for (int d = 0; d < 2; ++d) {
        const int gs   = d ? GS_C : GS_R;
        const int ng   = d ? ngc : ngr;
        const int mask = (1 << gs) - 1;
        const int* kidx = d ? col_idx : row_idx;
        const int* oidx = d ? row_idx : col_idx;
        const int* cp  = d ? cntC : cntR;
        const int* gp  = d ? gposC : gposR;
        float4*    pd  = d ? pay_c : pay_r;

        // load this chunk's group counts (coalesced row of khist2 output)
        for (int k = tid; k < ng; k += 256) cnt[k] = cp[(size_t)b * ng + k];
        if (tid == 0) cnt[ng] = 0;
        __syncthreads();

        // parallel exclusive scan of cnt[0..ng] (scratch = gofb[0..255])
        const int ipt = (ng + 1 + 255) >> 8;   // items/thread: 3 (row), 4 (col)
        int c4[4];
        int s = 0;
#pragma unroll
        for (int u = 0; u < 4; ++u) {
            const int k = tid * ipt + u;
            c4[u] = (u < ipt && k <= ng) ? cnt[k] : 0;
            s += c4[u];
        }
        gofb[tid] = s;
        __syncthreads();
        for (int dd = 1; dd < 256; dd <<= 1) {
            const int uu = (tid >= dd) ? gofb[tid - dd] : 0;
            __syncthreads();
            gofb[tid] += uu;
            __syncthreads();
        }
        int ex = gofb[tid] - s;
        __syncthreads();                        // gofb reads done; safe to reuse
#pragma unroll
        for (int u = 0; u < 4; ++u) {
            const int k = tid * ipt + u;
            if (u < ipt && k <= ng) { off[k] = ex; cnt[k] = ex; ex += c4[u]; }
        }
        __syncthreads();

        // prestage global positions + token counting-sort into LDS
        for (int k = tid; k < ng; k += 256) gofb[k] = gp[(size_t)k * NB + b];
        for (int k = tid; k < lim; k += 256) {
            const int grp = kidx[base + k] >> gs;
            const int pos = atomicAdd(&cnt[grp], 1);
            sp[pos] = (unsigned short)k;
        }
        __syncthreads();

        // grouped write: slot k -> token t; re-read edge (L1/L2-hot slice),
        // compute e (bitwise-same), write piecewise-contiguous runs.
        for (int k = tid; k < lim; k += 256) {
            const int t   = sp[k];
            const int key = kidx[base + t];
            const int oth = oidx[base + t];
            const int r   = d ? oth : key;
            const int c   = d ? key : oth;
            const float xv = s_score[c] + t_score[r];
            const float e  = xv >= 0.f ? xv : NEG_SLOPE * xv;
            const int grp = key >> gs;
            pd[(size_t)gofb[grp] + (k - off[grp])] =
                make_float4(__int_as_float(oth | ((key & mask) << 20)),
                            e, nbhd[base + t], 0.f);
        }
        __syncthreads();
    }
}

// ---------------------------------------------------------------------------
// Stage 4 (kept): IN-PLACE per-group key sort. Dense read -> LDS SoA +
// histogram -> 16-bit perm -> dense sorted writeback + per-key offsets koff.
// ---------------------------------------------------------------------------
__global__ void __launch_bounds__(512)
ksort_kernel(float4* __restrict__ pay,
             const int* __restrict__ goff,
             int* __restrict__ koff,
             int kpg, int cap) {
    extern __shared__ char sm[];
    int*    PO   = (int*)sm;                                  // cap
    float*  E    = (float*)(sm + (size_t)cap * 4);            // cap
    float*  B    = (float*)(sm + (size_t)cap * 8);            // cap
    unsigned short* perm = (unsigned short*)(sm + (size_t)cap * 12); // cap
    int*    scnt = (int*)(sm + (size_t)cap * 14);             // kpg
    int*    soff = scnt + kpg;                                // kpg+1
    int*    scur = soff + kpg + 1;                            // kpg

    const int g    = blockIdx.x;
    const int tid  = threadIdx.x;
    const int mask = kpg - 1;

    const int beg = goff[g];
    const int n   = min(goff[g + 1] - beg, cap);

    for (int k = tid; k < kpg; k += 512) scnt[k] = 0;
    __syncthreads();

    for (int k = tid; k < n; k += 512) {
        const float4 p = pay[(size_t)beg + k];
        const int pk = __float_as_int(p.x);
        PO[k] = pk; E[k] = p.y; B[k] = p.z;
        atomicAdd(&scnt[(pk >> 20) & mask], 1);
    }
    __syncthreads();

    if (tid == 0) {
        int a = 0;
        for (int k = 0; k < kpg; ++k) { const int t = scnt[k]; soff[k] = a; scur[k] = a; a += t; }
        soff[kpg] = a;
    }
    __syncthreads();

    for (int k = tid; k < n; k += 512)
        perm[atomicAdd(&scur[(PO[k] >> 20) & mask], 1)] = (unsigned short)k;
    __syncthreads();

    // sorted dense writeback (all reads done before this point -> in-place ok)
    for (int k = tid; k < n; k += 512) {
        const int kk = perm[k];
        pay[(size_t)beg + k] = make_float4(__int_as_float(PO[kk]), E[kk], B[kk], 0.f);
    }
    for (int k = tid; k <= kpg; k += 512)
        koff[(size_t)g * (kpg + 1) + k] = beg + soff[k];
}

// ---------------------------------------------------------------------------
// Stage 5 (kept): VERBATIM wave-per-key accum (f64 ers, same weight formula,
// 16-lane gather + butterfly), LDS-free, dense contiguous per-key segments.
// ---------------------------------------------------------------------------
__global__ void kaccum2_kernel(const int* __restrict__ koff, int kshift,
                               const float4* __restrict__ pay,
                               const float* __restrict__ other_msg,
                               float* __restrict__ out, int n_mine) {
    const int wave = (int)((blockIdx.x * (size_t)blockDim.x + threadIdx.x) >> 6);
    const int lane = threadIdx.x & 63;
    if (wave >= n_mine) return;

    const int kpg = 1 << kshift;
    const int grp = wave >> kshift;
    const int jk  = wave & (kpg - 1);
    const int beg = koff[(size_t)grp * (kpg + 1) + jk];
    const int end = koff[(size_t)grp * (kpg + 1) + jk + 1];

    double psum = 0.0;
    for (int k = beg + lane; k < end; k += 64) psum += (double)pay[k].y;
#pragma unroll
    for (int o = 32; o > 0; o >>= 1) psum += __shfl_down(psum, o, 64);
    double ers = __shfl(psum, 0, 64);
    if (ers == 0.0) ers = 1.0;
    const double inv = 1.0 / ers;

    const int g = lane >> 4;
    const int q = lane & 15;
    const float4* msg4 = (const float4*)other_msg;
    float4 acc = make_float4(0.f, 0.f, 0.f, 0.f);

    for (int kb = beg; kb < end; kb += 64) {
        const int k = kb + lane;
        int o = 0; float wt = 0.f;
        if (k < end) {
            float4 p = pay[k];
            o  = __float_as_int(p.x) & 0xFFFFF;
            wt = (float)((double)p.y * inv) * p.z;
        }
        const int cnt = min(64, end - kb);
        for (int j = 0; j < cnt; j += 4) {
            const int   jj = j + g;
            const int   oj = __shfl(o,  jj, 64);
            const float wj = __shfl(wt, jj, 64);
            float4 m = msg4[((size_t)oj << 4) + q];
            acc.x += wj * m.x;
            acc.y += wj * m.y;
            acc.z += wj * m.z;
            acc.w += wj * m.w;
        }
    }

#pragma unroll
    for (int d = 16; d < 64; d <<= 1) {
        acc.x += __shfl_xor(acc.x, d, 64);
        acc.y += __shfl_xor(acc.y, d, 64);
        acc.z += __shfl_xor(acc.z, d, 64);
        acc.w += __shfl_xor(acc.w, d, 64);
    }
    if (g == 0) ((float4*)out)[((size_t)wave << 4) + q] = acc;
}

// ===========================================================================
// FALLBACK PATH (R7, proven): hist -> scan -> per-direction scatter -> accum.
// Used only if ws_size can't hold the sort-path payload (~102 MB).
// ===========================================================================
__global__ void hist_kernel(const int* __restrict__ row_idx,
                            const int* __restrict__ col_idx,
                            int* __restrict__ cnt, int col_base, int nnz) {
    const int i = blockIdx.x * blockDim.x + threadIdx.x;
    if (i >= nnz) return;
    const int s = i & (SUB - 1);
    atomicAdd(&cnt[(row_idx[i] << SUB_SHIFT) + s], 1);
    atomicAdd(&cnt[col_base + (col_idx[i] << SUB_SHIFT) + s], 1);
}

__global__ void scan_stage1(const int* __restrict__ cnt, int* __restrict__ bsum,
                            int n) {
    __shared__ int lds[256];
    const int t = threadIdx.x;
    const int base = blockIdx.x * SCAN_CHUNK;
    int s = 0;
    for (int k = t; k < SCAN_CHUNK; k += 256) {
        const int j = base + k;
        if (j < n) s += cnt[j];
    }
    lds[t] = s;
    __syncthreads();
    for (int d = 128; d > 0; d >>= 1) {
        if (t < d) lds[t] += lds[t + d];
        __syncthreads();
    }
    if (t == 0) bsum[blockIdx.x] = lds[0];
}

__global__ void scan_stage2(int* __restrict__ bsum, int nb) {
    __shared__ int lds[1024];
    const int t = threadIdx.x;
    const int v = (t < nb) ? bsum[t] : 0;
    lds[t] = v;
    __syncthreads();
    for (int d = 1; d < 1024; d <<= 1) {
        int u = (t >= d) ? lds[t - d] : 0;
        __syncthreads();
        lds[t] += u;
        __syncthreads();
    }
    if (t < nb) bsum[t] = lds[t] - v;
}

__global__ void scan_stage3(const int* __restrict__ cnt,
                            const int* __restrict__ bsum,
                            int* __restrict__ off, int* __restrict__ cur,
                            int n, int total) {
    __shared__ int lds[256];
    const int t = threadIdx.x;
    const int base = blockIdx.x * SCAN_CHUNK + t * 16;
    int c[16];
    int s = 0;
#pragma unroll
    for (int k = 0; k < 16; ++k) {
        const int j = base + k;
        c[k] = (j < n) ? cnt[j] : 0;
        s += c[k];
    }
    lds[t] = s;
    __syncthreads();
    for (int d = 1; d < 256; d <<= 1) {
        int u = (t >= d) ? lds[t - d] : 0;
        __syncthreads();
        lds[t] += u;
        __syncthreads();
    }
    int ex = bsum[blockIdx.x] + lds[t] - s;
#pragma unroll
    for (int k = 0; k < 16; ++k) {
        const int j = base + k;
        if (j < n) { off[j] = ex; cur[j] = ex; ex += c[k]; }
    }
    if (blockIdx.x == 0 && t == 0) off[n] = total;
}

__global__ void scatter_row_kernel(const int* __restrict__ row_idx,
                                   const int* __restrict__ col_idx,
                                   const float* __restrict__ nbhd,
                                   const float* __restrict__ s_score,
                                   const float* __restrict__ t_score,
                                   int* __restrict__ cur,
                                   float4* __restrict__ pay, int nnz) {
    const int i = blockIdx.x * blockDim.x + threadIdx.x;
    if (i >= nnz) return;
    const int r = row_idx[i];
    const int c = col_idx[i];
    const float xv = s_score[c] + t_score[r];
    const float e  = xv >= 0.f ? xv : NEG_SLOPE * xv;
    const int p = atomicAdd(&cur[(r << SUB_SHIFT) + (i & (SUB - 1))], 1);
    pay[p] = make_float4(__int_as_float(c), e, nbhd[i], 0.f);
}

__global__ void scatter_col_kernel(const int* __restrict__ row_idx,
                                   const int* __restrict__ col_idx,
                                   const float* __restrict__ nbhd,
                                   const float* __restrict__ s_score,
                                   const float* __restrict__ t_score,
                                   int* __restrict__ cur, int col_base,
                                   float4* __restrict__ pay, int nnz) {
    const int i = blockIdx.x * blockDim.x + threadIdx.x;
    if (i >= nnz) return;
    const int r = row_idx[i];
    const int c = col_idx[i];
    const float xv = s_score[c] + t_score[r];
    const float e  = xv >= 0.f ? xv : NEG_SLOPE * xv;
    const int p = atomicAdd(&cur[col_base + (c << SUB_SHIFT) + (i & (SUB - 1))], 1);
    pay[p] = make_float4(__int_as_float(r), e, nbhd[i], 0.f);
}

__global__ void accum_kernel(const int* __restrict__ off, int off_base,
                             const float4* __restrict__ pay,
                             const float* __restrict__ other_msg,
                             float* __restrict__ out, int n_mine) {
    const int wave = (int)((blockIdx.x * (size_t)blockDim.x + threadIdx.x) >> 6);
    const int lane = threadIdx.x & 63;
    if (wave >= n_mine) return;

    const int beg = off[off_base + (wave << SUB_SHIFT)];
    const int end = off[off_base + (wave << SUB_SHIFT) + SUB];

    double psum = 0.0;
    for (int k = beg + lane; k < end; k += 64) psum += (double)pay[k].y;
#pragma unroll
    for (int o = 32; o > 0; o >>= 1) psum += __shfl_down(psum, o, 64);
    double ers = __shfl(psum, 0, 64);
    if (ers == 0.0) ers = 1.0;
    const double inv = 1.0 / ers;

    const int g = lane >> 4;
    const int q = lane & 15;
    const float4* msg4 = (const float4*)other_msg;
    float4 acc = make_float4(0.f, 0.f, 0.f, 0.f);

    for (int kb = beg; kb < end; kb += 64) {
        const int k = kb + lane;
        int o = 0; float wt = 0.f;
        if (k < end) {
            float4 p = pay[k];
            o  = __float_as_int(p.x);
            wt = (float)((double)p.y * inv) * p.z;
        }
        const int cnt = min(64, end - kb);
        for (int j = 0; j < cnt; j += 4) {
            const int   jj = j + g;
            const int   oj = __shfl(o,  jj, 64);
            const float wj = __shfl(wt, jj, 64);
            float4 m = msg4[((size_t)oj << 4) + q];
            acc.x += wj * m.x;
            acc.y += wj * m.y;
            acc.z += wj * m.z;
            acc.w += wj * m.w;
        }
    }

#pragma unroll
    for (int d = 16; d < 64; d <<= 1) {
        acc.x += __shfl_xor(acc.x, d, 64);
        acc.y += __shfl_xor(acc.y, d, 64);
        acc.z += __shfl_xor(acc.z, d, 64);
        acc.w += __shfl_xor(acc.w, d, 64);
    }
    if (g == 0) ((float4*)out)[((size_t)wave << 4) + q] = acc;
}

// ---------------------------------------------------------------------------
extern "C" void kernel_launch(void* const* d_in, const int* in_sizes, int n_in,
                              void* d_out, int out_size, void* d_ws, size_t ws_size,
                              hipStream_t stream) {
    const float* x_source = (const float*)d_in[0];
    const float* x_target = (const float*)d_in[1];
    const float* nbhd     = (const float*)d_in[2];
    const float* w_s      = (const float*)d_in[3];
    const float* w_t      = (const float*)d_in[4];
    const float* att      = (const float*)d_in[5];
    const int*   row_idx  = (const int*)d_in[6];
    const int*   col_idx  = (const int*)d_in[7];

    const int n_s = in_sizes[0] / D_IN;   // 100000
    const int n_t = in_sizes[1] / D_IN;   // 20000
    const int nnz = in_sizes[2];          // 2000000

    float* out = (float*)d_out;
    float* mos = out;                          // (n_s, 64)
    float* mot = out + (size_t)n_s * D_OUT;    // (n_t, 64)

    // common workspace head
    char* ws = (char*)d_ws;
    float* s_msg   = (float*)ws;  ws += sizeof(float) * (size_t)n_s * D_OUT;
    float* t_msg   = (float*)ws;  ws += sizeof(float) * (size_t)n_t * D_OUT;
    float* s_score = (float*)ws;  ws += sizeof(float) * (size_t)n_s;
    float* t_score = (float*)ws;  ws += sizeof(float) * (size_t)n_t;

    // R15 grouped-sort tail
    const int NBCH = (nnz + CHUNK - 1) / CHUNK;          // 977
    const int NGR  = (n_t + (1 << GS_R) - 1) >> GS_R;    // 625
    const int NGC  = (n_s + (1 << GS_C) - 1) >> GS_C;    // 782
    char* wsb = ws;
    int* cntR  = (int*)wsb;  wsb += sizeof(int) * (size_t)NBCH * NGR;
    int* cntC  = (int*)wsb;  wsb += sizeof(int) * (size_t)NBCH * NGC;
    int* gposR = (int*)wsb;  wsb += sizeof(int) * (size_t)NGR * NBCH;
    int* gposC = (int*)wsb;  wsb += sizeof(int) * (size_t)NGC * NBCH;
    int* gtotR = (int*)wsb;  wsb += sizeof(int) * (size_t)NGR;
    int* goffR = (int*)wsb;  wsb += sizeof(int) * (size_t)(NGR + 1);
    int* gtotC = (int*)wsb;  wsb += sizeof(int) * (size_t)NGC;
    int* goffC = (int*)wsb;  wsb += sizeof(int) * (size_t)(NGC + 1);
    int* koffR = (int*)wsb;  wsb += sizeof(int) * (size_t)NGR * ((1 << GS_R) + 1);
    int* koffC = (int*)wsb;  wsb += sizeof(int) * (size_t)NGC * ((1 << GS_C) + 1);
    wsb = (char*)(((uintptr_t)wsb + 15) & ~(uintptr_t)15);
    float4* pay_r = (float4*)wsb;  wsb += sizeof(float4) * (size_t)nnz;
    float4* pay_c = (float4*)wsb;  wsb += sizeof(float4) * (size_t)nnz;
    const size_t need_sort = (size_t)(wsb - (char*)d_ws);

    // 1) messages + scores (bitwise-stable path)
    msg_score8_kernel<<<(n_s + RPB - 1) / RPB, 256, 0, stream>>>(
        x_source, w_s, att, 0, s_msg, s_score, n_s);
    msg_score8_kernel<<<(n_t + RPB - 1) / RPB, 256, 0, stream>>>(
        x_target, w_t, att, D_OUT, t_msg, t_score, n_t);

    if (ws_size >= need_sort) {
        // ---------------- R15 grouped-sort path ----------------
        khist2_kernel<<<NBCH, 256, (size_t)(NGR + NGC) * 4, stream>>>(
            row_idx, col_idx, cntR, cntC, nnz, NGR, NGC);

        kgsum_kernel<<<NGR, 256, 0, stream>>>(cntR, gtotR, NBCH, NGR);
        kgsum_kernel<<<NGC, 256, 0, stream>>>(cntC, gtotC, NBCH, NGC);
        kgscan2_kernel<<<2, 1024, 0, stream>>>(gtotR, goffR, NGR, gtotC, goffC, NGC);
        kgpos_kernel<<<NGR, 256, 0, stream>>>(cntR, goffR, gposR, NBCH, NGR);
        kgpos_kernel<<<NGC, 256, 0, stream>>>(cntC, goffC, gposC, NBCH, NGC);

        const size_t smem_part = (size_t)CHUNK * 2 + (size_t)(3 * NGC + 2) * 4;
        kpart4_kernel<<<NBCH, 256, smem_part, stream>>>(
            row_idx, col_idx, nbhd, s_score, t_score,
            cntR, cntC, gposR, gposC, pay_r, pay_c, nnz, NBCH, NGR, NGC);

        const size_t smem_s_r = (size_t)CAPB_R * 14 + (size_t)(3 * (1 << GS_R) + 2) * 4;
        const size_t smem_s_c = (size_t)CAPB_C * 14 + (size_t)(3 * (1 << GS_C) + 2) * 4;
        ksort_kernel<<<NGR, 512, smem_s_r, stream>>>(
            pay_r, goffR, koffR, 1 << GS_R, CAPB_R);
        ksort_kernel<<<NGC, 512, smem_s_c, stream>>>(
            pay_c, goffC, koffC, 1 << GS_C, CAPB_C);

        kaccum2_kernel<<<(int)(((size_t)n_t * 64 + 255) / 256), 256, 0, stream>>>(
            koffR, GS_R, pay_r, s_msg, mot, n_t);
        kaccum2_kernel<<<(int)(((size_t)n_s * 64 + 255) / 256), 256, 0, stream>>>(
            koffC, GS_C, pay_c, t_msg, mos, n_s);
    } else {
        // ---------------- fallback: R7 hist+scan+sort path ----------------
        const int col_base = n_t * SUB;
        const int n_cnt    = (n_t + n_s) * SUB;
        const int total    = 2 * nnz;

        char* wsf = ws;
        int* cnt  = (int*)wsf;  wsf += sizeof(int) * (size_t)n_cnt;
        int* cur  = (int*)wsf;  wsf += sizeof(int) * (size_t)n_cnt;
        int* off  = (int*)wsf;  wsf += sizeof(int) * (size_t)(n_cnt + 1);
        int* bsum = (int*)wsf;  wsf += sizeof(int) * 1024;
        wsf = (char*)(((uintptr_t)wsf + 15) & ~(uintptr_t)15);
        float4* pay = (float4*)wsf;

        hipMemsetAsync(cnt, 0, sizeof(int) * (size_t)n_cnt, stream);

        hist_kernel<<<(nnz + 255) / 256, 256, 0, stream>>>(
            row_idx, col_idx, cnt, col_base, nnz);

        const int nb = (n_cnt + SCAN_CHUNK - 1) / SCAN_CHUNK;
        scan_stage1<<<nb, 256, 0, stream>>>(cnt, bsum, n_cnt);
        scan_stage2<<<1, 1024, 0, stream>>>(bsum, nb);
        scan_stage3<<<nb, 256, 0, stream>>>(cnt, bsum, off, cur, n_cnt, total);

        scatter_row_kernel<<<(nnz + 255) / 256, 256, 0, stream>>>(
            row_idx, col_idx, nbhd, s_score, t_score, cur, pay, nnz);
        scatter_col_kernel<<<(nnz + 255) / 256, 256, 0, stream>>>(
            row_idx, col_idx, nbhd, s_score, t_score, cur, col_base, pay, nnz);

        accum_kernel<<<(int)(((size_t)n_t * 64 + 255) / 256), 256, 0, stream>>>(
            off, 0, pay, s_msg, mot, n_t);
        accum_kernel<<<(int)(((size_t)n_s * 64 + 255) / 256), 256, 0, stream>>>(
            off, col_base, pay, t_msg, mos, n_s);
    }
}

// Round 10
// 467.063 us; speedup vs baseline: 1.4601x; 1.0018x over previous
//
#include <hip/hip_runtime.h>
#include <stdint.h>

#define D_IN  128
#define D_OUT 64
#define NEG_SLOPE 0.2f
#define SUB       8      // (fallback path) sub-bins per key
#define SUB_SHIFT 3
#define SCAN_CHUNK 4096
#define RPW       8      // rows per wave in msg_score8
#define RPB       32     // rows per block

// ---- R16 grouped-sort path ----
#define CHUNK   2048     // edges per chunk
#define GS_R    5        // rows: group = r>>5  -> 625 groups of 32 keys
#define GS_C    7        // cols: group = c>>7  -> 782 groups of 128 keys
#define CAPB_R  3712     // per row-group capacity (mean 3200, +9 sigma)
#define CAPB_C  3072     // per col-group capacity (mean 2560, +10 sigma)

// ---------------------------------------------------------------------------
// Fused skinny GEMM + attention score, 8 rows per wave, x staged in LDS.
// NUMERICS ARE BITWISE-IDENTICAL to the R4/R6/R7 passing path (absmax=128).
// DO NOT reassociate (R5 failed at 768 from an algebraically-equal variant).
// ---------------------------------------------------------------------------
__global__ void msg_score8_kernel(const float* __restrict__ x,
                                  const float* __restrict__ w,
                                  const float* __restrict__ att, int att_off,
                                  float* __restrict__ msg,
                                  float* __restrict__ score,
                                  int n_rows) {
    __shared__ float wl[D_IN * D_OUT];           // 32 KB
    __shared__ float xs[RPB * D_IN];             // 16 KB
    const int tid = threadIdx.x;

    const float4* w4  = (const float4*)w;
    float4*       wl4 = (float4*)wl;
#pragma unroll
    for (int i = 0; i < 8; ++i) wl4[tid + i * 256] = w4[tid + i * 256];

    const int rb = blockIdx.x * RPB;
    float4* xs4 = (float4*)xs;
    const float4* x4 = (const float4*)x;
#pragma unroll
    for (int i = 0; i < 4; ++i) {
        const int f  = tid + i * 256;
        const int r  = f >> 5;
        const int k4 = f & 31;
        const int row = min(rb + r, n_rows - 1);
        xs4[f] = x4[(size_t)row * 32 + k4];
    }
    __syncthreads();

    const int wv = tid >> 6;
    const int j  = tid & 63;
    const int rl = wv * RPW;
    const float4* xw = (const float4*)(xs + rl * D_IN);

    float acc[RPW];
#pragma unroll
    for (int r = 0; r < RPW; ++r) acc[r] = 0.f;

#pragma unroll 2
    for (int k4 = 0; k4 < D_IN / 4; ++k4) {
        const float w0 = wl[(k4 * 4 + 0) * D_OUT + j];
        const float w1 = wl[(k4 * 4 + 1) * D_OUT + j];
        const float w2 = wl[(k4 * 4 + 2) * D_OUT + j];
        const float w3 = wl[(k4 * 4 + 3) * D_OUT + j];
#pragma unroll
        for (int r = 0; r < RPW; ++r) {
            const float4 xv = xw[r * 32 + k4];
            acc[r] += xv.x * w0;
            acc[r] += xv.y * w1;
            acc[r] += xv.z * w2;
            acc[r] += xv.w * w3;
        }
    }

    const float aj = att[att_off + j];
#pragma unroll
    for (int r = 0; r < RPW; ++r) {
        const int row = rb + rl + r;
        if (row < n_rows) msg[(size_t)row * D_OUT + j] = acc[r];
        float v = acc[r] * aj;
#pragma unroll
        for (int off = 32; off > 0; off >>= 1) v += __shfl_down(v, off, 64);
        if (j == 0 && row < n_rows) score[row] = v;
    }
}

// ---------------------------------------------------------------------------
// Stage 1 (kept): per-chunk histograms for both directions in one pass.
// ---------------------------------------------------------------------------
__global__ void __launch_bounds__(256)
khist2_kernel(const int* __restrict__ row_idx, const int* __restrict__ col_idx,
              int* __restrict__ cntR, int* __restrict__ cntC,
              int nnz, int ngr, int ngc) {
    extern __shared__ int hs[];
    int* hr = hs;
    int* hc = hs + ngr;
    const int tid  = threadIdx.x;
    const int base = blockIdx.x * CHUNK;
    const int lim  = min(CHUNK, nnz - base);

    for (int k = tid; k < ngr + ngc; k += 256) hs[k] = 0;
    __syncthreads();
    for (int k = tid; k < lim; k += 256) {
        atomicAdd(&hr[row_idx[base + k] >> GS_R], 1);
        atomicAdd(&hc[col_idx[base + k] >> GS_C], 1);
    }
    __syncthreads();
    for (int g = tid; g < ngr; g += 256) cntR[(size_t)blockIdx.x * ngr + g] = hr[g];
    for (int g = tid; g < ngc; g += 256) cntC[(size_t)blockIdx.x * ngc + g] = hc[g];
}

__global__ void __launch_bounds__(256)
kgsum_kernel(const int* __restrict__ cnt, int* __restrict__ gtot,
             int NB, int ng) {
    __shared__ int lds[256];
    const int g = blockIdx.x;
    const int t = threadIdx.x;
    int s = 0;
    for (int b = t; b < NB; b += 256) s += cnt[(size_t)b * ng + g];
    lds[t] = s;
    __syncthreads();
    for (int d = 128; d > 0; d >>= 1) {
        if (t < d) lds[t] += lds[t + d];
        __syncthreads();
    }
    if (t == 0) gtot[g] = lds[0];
}

__global__ void __launch_bounds__(1024)
kgscan2_kernel(const int* __restrict__ gtotR, int* __restrict__ goffR, int ngr,
               const int* __restrict__ gtotC, int* __restrict__ goffC, int ngc) {
    __shared__ int lds[1024];
    const int t = threadIdx.x;
    const int* gt = blockIdx.x ? gtotC : gtotR;
    int*       go = blockIdx.x ? goffC : goffR;
    const int  n  = blockIdx.x ? ngc : ngr;
    const int v = (t < n) ? gt[t] : 0;
    lds[t] = v;
    __syncthreads();
    for (int d = 1; d < 1024; d <<= 1) {
        int u = (t >= d) ? lds[t - d] : 0;
        __syncthreads();
        lds[t] += u;
        __syncthreads();
    }
    if (t < n) go[t] = lds[t] - v;
    if (t == n - 1) go[n] = lds[t];
}

// 4 items/thread -> supports NB up to 1024 (NBCH = 977 at CHUNK=2048)
__global__ void __launch_bounds__(256)
kgpos_kernel(const int* __restrict__ cnt, const int* __restrict__ goff,
             int* __restrict__ gpos, int NB, int ng) {
    __shared__ int lds[256];
    const int g = blockIdx.x;
    const int t = threadIdx.x;
    int c[4];
    int s = 0;
#pragma unroll
    for (int u = 0; u < 4; ++u) {
        const int b = 4 * t + u;
        c[u] = (b < NB) ? cnt[(size_t)b * ng + g] : 0;
        s += c[u];
    }
    lds[t] = s;
    __syncthreads();
    for (int d = 1; d < 256; d <<= 1) {
        int u = (t >= d) ? lds[t - d] : 0;
        __syncthreads();
        lds[t] += u;
        __syncthreads();
    }
    int ex = goff[g] + lds[t] - s;
#pragma unroll
    for (int u = 0; u < 4; ++u) {
        const int b = 4 * t + u;
        if (b < NB) { gpos[(size_t)g * NB + b] = ex; ex += c[u]; }
    }
}

// ---------------------------------------------------------------------------
// R16 stage 3: kpart5 — R15's 2-byte token sort, SPLIT BY DIRECTION.
// R15 was grid-limited: 977 blocks = 3.8/CU -> 32% occupancy, each block
// serializing both directions through barriers. Grid is now 2*NB blocks;
// block handles one direction only (d = blockIdx.x >= NB). Same counts,
// same parallel scan, same token sort, byte-identical grouped write
// (proven WRITE ~83MB piecewise-coalesced pattern). Pure scheduling change.
// ---------------------------------------------------------------------------
__global__ void __launch_bounds__(256)
kpart5_kernel(const int* __restrict__ row_idx,
              const int* __restrict__ col_idx,
              const float* __restrict__ nbhd,
              const float* __restrict__ s_score,
              const float* __restrict__ t_score,
              const int* __restrict__ cntR, const int* __restrict__ cntC,
              const int* __restrict__ gposR, const int* __restrict__ gposC,
              float4* __restrict__ pay_r, float4* __restrict__ pay_c,
              int nnz, int NB, int ngr, int ngc) {
    extern __shared__ char sm[];
    unsigned short* sp = (unsigned short*)sm;        // CHUNK tokens (4KB)
    int* cnt  = (int*)(sm + (size_t)CHUNK * 2);      // ng+1 (cursors)
    int* off  = cnt + (ngc + 1);                     // ng+1
    int* gofb = off + (ngc + 1);                     // ng (scan scratch first)

    const int tid  = threadIdx.x;
    const int d    = (blockIdx.x >= NB) ? 1 : 0;
    const int b    = blockIdx.x - (d ? NB : 0);
    const int base = b * CHUNK;
    const int lim  = min(CHUNK, nnz - base);

    const int gs   = d ? GS_C : GS_R;
    const int ng   = d ? ngc : ngr;
    const int mask = (1 << gs) - 1;
    const int* kidx = d ? col_idx : row_idx;
    const int* oidx = d ? row_idx : col_idx;
    const int* cp  = d ? cntC : cntR;
    const int* gp  = d ? gposC : gposR;
    float4*    pd  = d ? pay_c : pay_r;

    // load this chunk's group counts (coalesced row of khist2 output)
    for (int k = tid; k < ng; k += 256) cnt[k] = cp[(size_t)b * ng + k];
    if (tid == 0) cnt[ng] = 0;
    __syncthreads();

    // parallel exclusive scan of cnt[0..ng] (scratch = gofb[0..255])
    const int ipt = (ng + 1 + 255) >> 8;   // items/thread: 3 (row), 4 (col)
    int c4[4];
    int s = 0;
#pragma unroll
    for (int u = 0; u < 4; ++u) {
        const int k = tid * ipt + u;
        c4[u] = (u < ipt && k <= ng) ? cnt[k] : 0;
        s += c4[u];
    }
    gofb[tid] = s;
    __syncthreads();
    for (int dd = 1; dd < 256; dd <<= 1) {
        const int uu = (tid >= dd) ? gofb[tid - dd] : 0;
        __syncthreads();
        gofb[tid] += uu;
        __syncthreads();
    }
    int ex = gofb[tid] - s;
    __syncthreads();                        // gofb reads done; safe to reuse
#pragma unroll
    for (int u = 0; u < 4; ++u) {
        const int k = tid * ipt + u;
        if (u < ipt && k <= ng) { off[k] = ex; cnt[k] = ex; ex += c4[u]; }
    }
    __syncthreads();

    // prestage global positions + token counting-sort into LDS
    for (int k = tid; k < ng; k += 256) gofb[k] = gp[(size_t)k * NB + b];
    for (int k = tid; k < lim; k += 256) {
        const int grp = kidx[base + k] >> gs;
        const int pos = atomicAdd(&cnt[grp], 1);
        sp[pos] = (unsigned short)k;
    }
    __syncthreads();

    // grouped write: slot k -> token t; re-read edge (L1/L2-hot slice),
    // compute e (bitwise-same), write piecewise-contiguous runs.
    for (int k = tid; k < lim; k += 256) {
        const int t   = sp[k];
        const int key = kidx[base + t];
        const int oth = oidx[base + t];
        const int r   = d ? oth : key;
        const int c   = d ? key : oth;
        const float xv = s_score[c] + t_score[r];
        const float e  = xv >= 0.f ? xv : NEG_SLOPE * xv;
        const int grp = key >> gs;
        pd[(size_t)gofb[grp] + (k - off[grp])] =
            make_float4(__int_as_float(oth | ((key & mask) << 20)),
                        e, nbhd[base + t], 0.f);
    }
}

// ---------------------------------------------------------------------------
// Stage 4 (kept): IN-PLACE per-group key sort. Dense read -> LDS SoA +
// histogram -> 16-bit perm -> dense sorted writeback + per-key offsets koff.
// ---------------------------------------------------------------------------
__global__ void __launch_bounds__(512)
ksort_kernel(float4* __restrict__ pay,
             const int* __restrict__ goff,
             int* __restrict__ koff,
             int kpg, int cap) {
    extern __shared__ char sm[];
    int*    PO   = (int*)sm;                                  // cap
    float*  E    = (float*)(sm + (size_t)cap * 4);            // cap
    float*  B    = (float*)(sm + (size_t)cap * 8);            // cap
    unsigned short* perm = (unsigned short*)(sm + (size_t)cap * 12); // cap
    int*    scnt = (int*)(sm + (size_t)cap * 14);             // kpg
    int*    soff = scnt + kpg;                                // kpg+1
    int*    scur = soff + kpg + 1;                            // kpg

    const int g    = blockIdx.x;
    const int tid  = threadIdx.x;
    const int mask = kpg - 1;

    const int beg = goff[g];
    const int n   = min(goff[g + 1] - beg, cap);

    for (int k = tid; k < kpg; k += 512) scnt[k] = 0;
    __syncthreads();

    for (int k = tid; k < n; k += 512) {
        const float4 p = pay[(size_t)beg + k];
        const int pk = __float_as_int(p.x);
        PO[k] = pk; E[k] = p.y; B[k] = p.z;
        atomicAdd(&scnt[(pk >> 20) & mask], 1);
    }
    __syncthreads();

    if (tid == 0) {
        int a = 0;
        for (int k = 0; k < kpg; ++k) { const int t = scnt[k]; soff[k] = a; scur[k] = a; a += t; }
        soff[kpg] = a;
    }
    __syncthreads();

    for (int k = tid; k < n; k += 512)
        perm[atomicAdd(&scur[(PO[k] >> 20) & mask], 1)] = (unsigned short)k;
    __syncthreads();

    // sorted dense writeback (all reads done before this point -> in-place ok)
    for (int k = tid; k < n; k += 512) {
        const int kk = perm[k];
        pay[(size_t)beg + k] = make_float4(__int_as_float(PO[kk]), E[kk], B[kk], 0.f);
    }
    for (int k = tid; k <= kpg; k += 512)
        koff[(size_t)g * (kpg + 1) + k] = beg + soff[k];
}

// ---------------------------------------------------------------------------
// Stage 5 (kept): VERBATIM wave-per-key accum (f64 ers, same weight formula,
// 16-lane gather + butterfly), LDS-free, dense contiguous per-key segments.
// ---------------------------------------------------------------------------
__global__ void kaccum2_kernel(const int* __restrict__ koff, int kshift,
                               const float4* __restrict__ pay,
                               const float* __restrict__ other_msg,
                               float* __restrict__ out, int n_mine) {
    const int wave = (int)((blockIdx.x * (size_t)blockDim.x + threadIdx.x) >> 6);
    const int lane = threadIdx.x & 63;
    if (wave >= n_mine) return;

    const int kpg = 1 << kshift;
    const int grp = wave >> kshift;
    const int jk  = wave & (kpg - 1);
    const int beg = koff[(size_t)grp * (kpg + 1) + jk];
    const int end = koff[(size_t)grp * (kpg + 1) + jk + 1];

    double psum = 0.0;
    for (int k = beg + lane; k < end; k += 64) psum += (double)pay[k].y;
#pragma unroll
    for (int o = 32; o > 0; o >>= 1) psum += __shfl_down(psum, o, 64);
    double ers = __shfl(psum, 0, 64);
    if (ers == 0.0) ers = 1.0;
    const double inv = 1.0 / ers;

    const int g = lane >> 4;
    const int q = lane & 15;
    const float4* msg4 = (const float4*)other_msg;
    float4 acc = make_float4(0.f, 0.f, 0.f, 0.f);

    for (int kb = beg; kb < end; kb += 64) {
        const int k = kb + lane;
        int o = 0; float wt = 0.f;
        if (k < end) {
            float4 p = pay[k];
            o  = __float_as_int(p.x) & 0xFFFFF;
            wt = (float)((double)p.y * inv) * p.z;
        }
        const int cnt = min(64, end - kb);
        for (int j = 0; j < cnt; j += 4) {
            const int   jj = j + g;
            const int   oj = __shfl(o,  jj, 64);
            const float wj = __shfl(wt, jj, 64);
            float4 m = msg4[((size_t)oj << 4) + q];
            acc.x += wj * m.x;
            acc.y += wj * m.y;
            acc.z += wj * m.z;
            acc.w += wj * m.w;
        }
    }

#pragma unroll
    for (int d = 16; d < 64; d <<= 1) {
        acc.x += __shfl_xor(acc.x, d, 64);
        acc.y += __shfl_xor(acc.y, d, 64);
        acc.z += __shfl_xor(acc.z, d, 64);
        acc.w += __shfl_xor(acc.w, d, 64);
    }
    if (g == 0) ((float4*)out)[((size_t)wave << 4) + q] = acc;
}

// ===========================================================================
// FALLBACK PATH (R7, proven): hist -> scan -> per-direction scatter -> accum.
// Used only if ws_size can't hold the sort-path payload (~102 MB).
// ===========================================================================
__global__ void hist_kernel(const int* __restrict__ row_idx,
                            const int* __restrict__ col_idx,
                            int* __restrict__ cnt, int col_base, int nnz) {
    const int i = blockIdx.x * blockDim.x + threadIdx.x;
    if (i >= nnz) return;
    const int s = i & (SUB - 1);
    atomicAdd(&cnt[(row_idx[i] << SUB_SHIFT) + s], 1);
    atomicAdd(&cnt[col_base + (col_idx[i] << SUB_SHIFT) + s], 1);
}

__global__ void scan_stage1(const int* __restrict__ cnt, int* __restrict__ bsum,
                            int n) {
    __shared__ int lds[256];
    const int t = threadIdx.x;
    const int base = blockIdx.x * SCAN_CHUNK;
    int s = 0;
    for (int k = t; k < SCAN_CHUNK; k += 256) {
        const int j = base + k;
        if (j < n) s += cnt[j];
    }
    lds[t] = s;
    __syncthreads();
    for (int d = 128; d > 0; d >>= 1) {
        if (t < d) lds[t] += lds[t + d];
        __syncthreads();
    }
    if (t == 0) bsum[blockIdx.x] = lds[0];
}

__global__ void scan_stage2(int* __restrict__ bsum, int nb) {
    __shared__ int lds[1024];
    const int t = threadIdx.x;
    const int v = (t < nb) ? bsum[t] : 0;
    lds[t] = v;
    __syncthreads();
    for (int d = 1; d < 1024; d <<= 1) {
        int u = (t >= d) ? lds[t - d] : 0;
        __syncthreads();
        lds[t] += u;
        __syncthreads();
    }
    if (t < nb) bsum[t] = lds[t] - v;
}

__global__ void scan_stage3(const int* __restrict__ cnt,
                            const int* __restrict__ bsum,
                            int* __restrict__ off, int* __restrict__ cur,
                            int n, int total) {
    __shared__ int lds[256];
    const int t = threadIdx.x;
    const int base = blockIdx.x * SCAN_CHUNK + t * 16;
    int c[16];
    int s = 0;
#pragma unroll
    for (int k = 0; k < 16; ++k) {
        const int j = base + k;
        c[k] = (j < n) ? cnt[j] : 0;
        s += c[k];
    }
    lds[t] = s;
    __syncthreads();
    for (int d = 1; d < 256; d <<= 1) {
        int u = (t >= d) ? lds[t - d] : 0;
        __syncthreads();
        lds[t] += u;
        __syncthreads();
    }
    int ex = bsum[blockIdx.x] + lds[t] - s;
#pragma unroll
    for (int k = 0; k < 16; ++k) {
        const int j = base + k;
        if (j < n) { off[j] = ex; cur[j] = ex; ex += c[k]; }
    }
    if (blockIdx.x == 0 && t == 0) off[n] = total;
}

__global__ void scatter_row_kernel(const int* __restrict__ row_idx,
                                   const int* __restrict__ col_idx,
                                   const float* __restrict__ nbhd,
                                   const float* __restrict__ s_score,
                                   const float* __restrict__ t_score,
                                   int* __restrict__ cur,
                                   float4* __restrict__ pay, int nnz) {
    const int i = blockIdx.x * blockDim.x + threadIdx.x;
    if (i >= nnz) return;
    const int r = row_idx[i];
    const int c = col_idx[i];
    const float xv = s_score[c] + t_score[r];
    const float e  = xv >= 0.f ? xv : NEG_SLOPE * xv;
    const int p = atomicAdd(&cur[(r << SUB_SHIFT) + (i & (SUB - 1))], 1);
    pay[p] = make_float4(__int_as_float(c), e, nbhd[i], 0.f);
}

__global__ void scatter_col_kernel(const int* __restrict__ row_idx,
                                   const int* __restrict__ col_idx,
                                   const float* __restrict__ nbhd,
                                   const float* __restrict__ s_score,
                                   const float* __restrict__ t_score,
                                   int* __restrict__ cur, int col_base,
                                   float4* __restrict__ pay, int nnz) {
    const int i = blockIdx.x * blockDim.x + threadIdx.x;
    if (i >= nnz) return;
    const int r = row_idx[i];
    const int c = col_idx[i];
    const float xv = s_score[c] + t_score[r];
    const float e  = xv >= 0.f ? xv : NEG_SLOPE * xv;
    const int p = atomicAdd(&cur[col_base + (c << SUB_SHIFT) + (i & (SUB - 1))], 1);
    pay[p] = make_float4(__int_as_float(r), e, nbhd[i], 0.f);
}

__global__ void accum_kernel(const int* __restrict__ off, int off_base,
                             const float4* __restrict__ pay,
                             const float* __restrict__ other_msg,
                             float* __restrict__ out, int n_mine) {
    const int wave = (int)((blockIdx.x * (size_t)blockDim.x + threadIdx.x) >> 6);
    const int lane = threadIdx.x & 63;
    if (wave >= n_mine) return;

    const int beg = off[off_base + (wave << SUB_SHIFT)];
    const int end = off[off_base + (wave << SUB_SHIFT) + SUB];

    double psum = 0.0;
    for (int k = beg + lane; k < end; k += 64) psum += (double)pay[k].y;
#pragma unroll
    for (int o = 32; o > 0; o >>= 1) psum += __shfl_down(psum, o, 64);
    double ers = __shfl(psum, 0, 64);
    if (ers == 0.0) ers = 1.0;
    const double inv = 1.0 / ers;

    const int g = lane >> 4;
    const int q = lane & 15;
    const float4* msg4 = (const float4*)other_msg;
    float4 acc = make_float4(0.f, 0.f, 0.f, 0.f);

    for (int kb = beg; kb < end; kb += 64) {
        const int k = kb + lane;
        int o = 0; float wt = 0.f;
        if (k < end) {
            float4 p = pay[k];
            o  = __float_as_int(p.x);
            wt = (float)((double)p.y * inv) * p.z;
        }
        const int cnt = min(64, end - kb);
        for (int j = 0; j < cnt; j += 4) {
            const int   jj = j + g;
            const int   oj = __shfl(o,  jj, 64);
            const float wj = __shfl(wt, jj, 64);
            float4 m = msg4[((size_t)oj << 4) + q];
            acc.x += wj * m.x;
            acc.y += wj * m.y;
            acc.z += wj * m.z;
            acc.w += wj * m.w;
        }
    }

#pragma unroll
    for (int d = 16; d < 64; d <<= 1) {
        acc.x += __shfl_xor(acc.x, d, 64);
        acc.y += __shfl_xor(acc.y, d, 64);
        acc.z += __shfl_xor(acc.z, d, 64);
        acc.w += __shfl_xor(acc.w, d, 64);
    }
    if (g == 0) ((float4*)out)[((size_t)wave << 4) + q] = acc;
}

// ---------------------------------------------------------------------------
extern "C" void kernel_launch(void* const* d_in, const int* in_sizes, int n_in,
                              void* d_out, int out_size, void* d_ws, size_t ws_size,
                              hipStream_t stream) {
    const float* x_source = (const float*)d_in[0];
    const float* x_target = (const float*)d_in[1];
    const float* nbhd     = (const float*)d_in[2];
    const float* w_s      = (const float*)d_in[3];
    const float* w_t      = (const float*)d_in[4];
    const float* att      = (const float*)d_in[5];
    const int*   row_idx  = (const int*)d_in[6];
    const int*   col_idx  = (const int*)d_in[7];

    const int n_s = in_sizes[0] / D_IN;   // 100000
    const int n_t = in_sizes[1] / D_IN;   // 20000
    const int nnz = in_sizes[2];          // 2000000

    float* out = (float*)d_out;
    float* mos = out;                          // (n_s, 64)
    float* mot = out + (size_t)n_s * D_OUT;    // (n_t, 64)

    // common workspace head
    char* ws = (char*)d_ws;
    float* s_msg   = (float*)ws;  ws += sizeof(float) * (size_t)n_s * D_OUT;
    float* t_msg   = (float*)ws;  ws += sizeof(float) * (size_t)n_t * D_OUT;
    float* s_score = (float*)ws;  ws += sizeof(float) * (size_t)n_s;
    float* t_score = (float*)ws;  ws += sizeof(float) * (size_t)n_t;

    // R16 grouped-sort tail
    const int NBCH = (nnz + CHUNK - 1) / CHUNK;          // 977
    const int NGR  = (n_t + (1 << GS_R) - 1) >> GS_R;    // 625
    const int NGC  = (n_s + (1 << GS_C) - 1) >> GS_C;    // 782
    char* wsb = ws;
    int* cntR  = (int*)wsb;  wsb += sizeof(int) * (size_t)NBCH * NGR;
    int* cntC  = (int*)wsb;  wsb += sizeof(int) * (size_t)NBCH * NGC;
    int* gposR = (int*)wsb;  wsb += sizeof(int) * (size_t)NGR * NBCH;
    int* gposC = (int*)wsb;  wsb += sizeof(int) * (size_t)NGC * NBCH;
    int* gtotR = (int*)wsb;  wsb += sizeof(int) * (size_t)NGR;
    int* goffR = (int*)wsb;  wsb += sizeof(int) * (size_t)(NGR + 1);
    int* gtotC = (int*)wsb;  wsb += sizeof(int) * (size_t)NGC;
    int* goffC = (int*)wsb;  wsb += sizeof(int) * (size_t)(NGC + 1);
    int* koffR = (int*)wsb;  wsb += sizeof(int) * (size_t)NGR * ((1 << GS_R) + 1);
    int* koffC = (int*)wsb;  wsb += sizeof(int) * (size_t)NGC * ((1 << GS_C) + 1);
    wsb = (char*)(((uintptr_t)wsb + 15) & ~(uintptr_t)15);
    float4* pay_r = (float4*)wsb;  wsb += sizeof(float4) * (size_t)nnz;
    float4* pay_c = (float4*)wsb;  wsb += sizeof(float4) * (size_t)nnz;
    const size_t need_sort = (size_t)(wsb - (char*)d_ws);

    // 1) messages + scores (bitwise-stable path)
    msg_score8_kernel<<<(n_s + RPB - 1) / RPB, 256, 0, stream>>>(
        x_source, w_s, att, 0, s_msg, s_score, n_s);
    msg_score8_kernel<<<(n_t + RPB - 1) / RPB, 256, 0, stream>>>(
        x_target, w_t, att, D_OUT, t_msg, t_score, n_t);

    if (ws_size >= need_sort) {
        // ---------------- R16 grouped-sort path ----------------
        khist2_kernel<<<NBCH, 256, (size_t)(NGR + NGC) * 4, stream>>>(
            row_idx, col_idx, cntR, cntC, nnz, NGR, NGC);

        kgsum_kernel<<<NGR, 256, 0, stream>>>(cntR, gtotR, NBCH, NGR);
        kgsum_kernel<<<NGC, 256, 0, stream>>>(cntC, gtotC, NBCH, NGC);
        kgscan2_kernel<<<2, 1024, 0, stream>>>(gtotR, goffR, NGR, gtotC, goffC, NGC);
        kgpos_kernel<<<NGR, 256, 0, stream>>>(cntR, goffR, gposR, NBCH, NGR);
        kgpos_kernel<<<NGC, 256, 0, stream>>>(cntC, goffC, gposC, NBCH, NGC);

        const size_t smem_part = (size_t)CHUNK * 2 + (size_t)(3 * NGC + 2) * 4;
        kpart5_kernel<<<2 * NBCH, 256, smem_part, stream>>>(
            row_idx, col_idx, nbhd, s_score, t_score,
            cntR, cntC, gposR, gposC, pay_r, pay_c, nnz, NBCH, NGR, NGC);

        const size_t smem_s_r = (size_t)CAPB_R * 14 + (size_t)(3 * (1 << GS_R) + 2) * 4;
        const size_t smem_s_c = (size_t)CAPB_C * 14 + (size_t)(3 * (1 << GS_C) + 2) * 4;
        ksort_kernel<<<NGR, 512, smem_s_r, stream>>>(
            pay_r, goffR, koffR, 1 << GS_R, CAPB_R);
        ksort_kernel<<<NGC, 512, smem_s_c, stream>>>(
            pay_c, goffC, koffC, 1 << GS_C, CAPB_C);

        kaccum2_kernel<<<(int)(((size_t)n_t * 64 + 255) / 256), 256, 0, stream>>>(
            koffR, GS_R, pay_r, s_msg, mot, n_t);
        kaccum2_kernel<<<(int)(((size_t)n_s * 64 + 255) / 256), 256, 0, stream>>>(
            koffC, GS_C, pay_c, t_msg, mos, n_s);
    } else {
        // ---------------- fallback: R7 hist+scan+sort path ----------------
        const int col_base = n_t * SUB;
        const int n_cnt    = (n_t + n_s) * SUB;
        const int total    = 2 * nnz;

        char* wsf = ws;
        int* cnt  = (int*)wsf;  wsf += sizeof(int) * (size_t)n_cnt;
        int* cur  = (int*)wsf;  wsf += sizeof(int) * (size_t)n_cnt;
        int* off  = (int*)wsf;  wsf += sizeof(int) * (size_t)(n_cnt + 1);
        int* bsum = (int*)wsf;  wsf += sizeof(int) * 1024;
        wsf = (char*)(((uintptr_t)wsf + 15) & ~(uintptr_t)15);
        float4* pay = (float4*)wsf;

        hipMemsetAsync(cnt, 0, sizeof(int) * (size_t)n_cnt, stream);

        hist_kernel<<<(nnz + 255) / 256, 256, 0, stream>>>(
            row_idx, col_idx, cnt, col_base, nnz);

        const int nb = (n_cnt + SCAN_CHUNK - 1) / SCAN_CHUNK;
        scan_stage1<<<nb, 256, 0, stream>>>(cnt, bsum, n_cnt);
        scan_stage2<<<1, 1024, 0, stream>>>(bsum, nb);
        scan_stage3<<<nb, 256, 0, stream>>>(cnt, bsum, off, cur, n_cnt, total);

        scatter_row_kernel<<<(nnz + 255) / 256, 256, 0, stream>>>(
            row_idx, col_idx, nbhd, s_score, t_score, cur, pay, nnz);
        scatter_col_kernel<<<(nnz + 255) / 256, 256, 0, stream>>>(
            row_idx, col_idx, nbhd, s_score, t_score, cur, col_base, pay, nnz);

        accum_kernel<<<(int)(((size_t)n_t * 64 + 255) / 256), 256, 0, stream>>>(
            off, 0, pay, s_msg, mot, n_t);
        accum_kernel<<<(int)(((size_t)n_s * 64 + 255) / 256), 256, 0, stream>>>(
            off, col_base, pay, t_msg, mos, n_s);
    }
}